// Round 7
// baseline (1462.478 us; speedup 1.0000x reference)
//
#include <hip/hip_runtime.h>
#include <hip/hip_bf16.h>
#include <math.h>

#define BATCH 64
#define CHUNK 32           // batch chunk for k/v scratch
#define INPUT_SIZE 10080
#define PATCH 18
#define SEQ 560            // S
#define EMB 96             // E
#define NHEAD 12           // H
#define HDIM 96            // D
#define FFDIM 256          // F
#define NLAYER 2
#define TOK (BATCH * SEQ)  // 35840 tokens
#define EPSV 1e-5f
#define SCALE 0.10206207261596577f      // 1/sqrt(96)
#define SCALE_L2E 0.14724443805513492f  // SCALE * log2(e): scores in log2 space

typedef __attribute__((ext_vector_type(8))) short bf16x8;  // 8 bf16 (4 VGPRs)
typedef __attribute__((ext_vector_type(4))) short bf16x4;  // 4 bf16 (8B store)
typedef __attribute__((ext_vector_type(4))) float f32x4;   // 4 fp32 acc
typedef __attribute__((ext_vector_type(2))) unsigned int u32x2;

static __device__ __forceinline__ short f2bf(float x) {
  union { __hip_bfloat16 b; short s; } u;
  u.b = __float2bfloat16(x);
  return u.s;
}

// pack two floats as 2 bf16 in one u32 (lo in low half)
static __device__ __forceinline__ unsigned int pack2bf(float lo, float hi) {
  unsigned int a = (unsigned short)f2bf(lo);
  unsigned int b = (unsigned short)f2bf(hi);
  return a | (b << 16);
}

// raw v_exp_f32: 2^x (scores are pre-scaled by log2(e))
static __device__ __forceinline__ float exp2_fast(float x) {
  float r;
  asm("v_exp_f32 %0, %1" : "=v"(r) : "v"(x));
  return r;
}

// ---------------- Kernel 0: all weight transposes, one launch --------------
__global__ __launch_bounds__(256) void allprep_kernel(
    const float* __restrict__ Wq, const float* __restrict__ Wk,
    const float* __restrict__ Wv, const float* __restrict__ Wo,
    const float* __restrict__ ff1_W, const float* __restrict__ ff2_W,
    __hip_bfloat16* __restrict__ wqT, __hip_bfloat16* __restrict__ wkvT,
    __hip_bfloat16* __restrict__ woT, __hip_bfloat16* __restrict__ ff1WT,
    __hip_bfloat16* __restrict__ ff2WT) {
  int bx = blockIdx.x;
  if (bx < 72) {
    int hh = bx % NHEAD, mat = (bx / NHEAD) % 3, l = bx / 36;
    const float* src = (mat == 0 ? Wq : (mat == 1 ? Wk : Wv)) +
                       ((size_t)l * NHEAD + hh) * EMB * HDIM;
    __shared__ float t[HDIM * 97];
    for (int i = threadIdx.x; i < EMB * HDIM; i += 256) {
      int e = i / HDIM, d = i % HDIM;
      t[d * 97 + e] = src[i];
    }
    __syncthreads();
    __hip_bfloat16* dst;
    if (mat == 0)
      dst = wqT + ((size_t)l * NHEAD + hh) * HDIM * EMB;
    else
      dst = wkvT + ((size_t)l * 2 * NHEAD * HDIM + (mat - 1) * NHEAD * HDIM +
                    hh * HDIM) * EMB;
    for (int j = threadIdx.x; j < HDIM * EMB; j += 256) {
      int d = j / EMB, e = j % EMB;
      dst[j] = __float2bfloat16(t[d * 97 + e]);
    }
  } else if (bx < 74) {
    int l = bx - 72;
    const float* src = Wo + (size_t)l * NHEAD * HDIM * EMB;
    __hip_bfloat16* dst = woT + (size_t)l * EMB * NHEAD * HDIM;
    for (int i = threadIdx.x; i < EMB * NHEAD * HDIM; i += 256) {
      int e = i / (NHEAD * HDIM), j = i % (NHEAD * HDIM);
      dst[i] = __float2bfloat16(src[(size_t)j * EMB + e]);
    }
  } else {
    int idx = bx - 74;
    int mat = idx % 2, l = idx / 2;
    if (mat == 0) {
      const float* src = ff1_W + (size_t)l * EMB * FFDIM;
      __hip_bfloat16* dst = ff1WT + (size_t)l * FFDIM * EMB;
      for (int i = threadIdx.x; i < FFDIM * EMB; i += 256) {
        int f = i / EMB, e = i % EMB;
        dst[i] = __float2bfloat16(src[(size_t)e * FFDIM + f]);
      }
    } else {
      const float* src = ff2_W + (size_t)l * FFDIM * EMB;
      __hip_bfloat16* dst = ff2WT + (size_t)l * EMB * FFDIM;
      for (int i = threadIdx.x; i < EMB * FFDIM; i += 256) {
        int e = i / FFDIM, f = i % FFDIM;
        dst[i] = __float2bfloat16(src[(size_t)f * EMB + e]);
      }
    }
  }
}

// ---------------- Kernel 1: patch embedding + sinusoidal PE ----------------
__global__ void patch_pe_kernel(const float* __restrict__ x,
                                const float* __restrict__ W,
                                const float* __restrict__ bias,
                                float* __restrict__ h,
                                __hip_bfloat16* __restrict__ hbf) {
  int gid = blockIdx.x * blockDim.x + threadIdx.x;
  if (gid >= TOK * EMB) return;
  int tok = gid / EMB;
  int e = gid % EMB;
  int b = tok / SEQ;
  int s = tok % SEQ;
  const float* xp = x + b * INPUT_SIZE + s * PATCH;
  float acc = bias[e];
#pragma unroll
  for (int p = 0; p < PATCH; p++) acc += xp[p] * W[p * EMB + e];
  int i = e >> 1;
  float freq = __expf(-(float)(2 * i) * (9.210340371976184f / 96.0f));
  float ang = (float)s * freq;
  acc += (e & 1) ? cosf(ang) : sinf(ang);
  h[gid] = acc;
  hbf[gid] = __float2bfloat16(acc);
}

// ---------------- Kernel 2: K/V projection GEMM (MFMA) ---------------------
__global__ __launch_bounds__(256) void kv_mfma_kernel(
    const __hip_bfloat16* __restrict__ hbf,
    const __hip_bfloat16* __restrict__ wkvT, const float* __restrict__ bk,
    const float* __restrict__ bv, __hip_bfloat16* __restrict__ kbuf,
    __hip_bfloat16* __restrict__ vbufT, int b0) {
  const int wave = threadIdx.x >> 6;
  const int lane = threadIdx.x & 63;
  const int tq = lane & 15;
  const int quad = lane >> 4;
  const int m0 = blockIdx.x * 64 + wave * 16;  // token tile row (chunk-local)
  const int n0 = blockIdx.y * 64;

  __shared__ short tile[4][16][68];  // wave-local K bounce (8.7 KB)

  const short* ap =
      (const short*)hbf + ((size_t)b0 * SEQ + m0 + tq) * EMB + quad * 8;
  bf16x8 a0 = *(const bf16x8*)(ap);
  bf16x8 a1 = *(const bf16x8*)(ap + 32);
  bf16x8 a2 = *(const bf16x8*)(ap + 64);

  f32x4 acc[4];
  const f32x4 zero4 = {0.f, 0.f, 0.f, 0.f};
#pragma unroll
  for (int nt = 0; nt < 4; nt++) acc[nt] = zero4;
#pragma unroll
  for (int nt = 0; nt < 4; nt++) {
    const short* bp =
        (const short*)wkvT + (size_t)(n0 + nt * 16 + tq) * EMB + quad * 8;
    bf16x8 b0f = *(const bf16x8*)(bp);
    bf16x8 b1f = *(const bf16x8*)(bp + 32);
    bf16x8 b2f = *(const bf16x8*)(bp + 64);
    acc[nt] = __builtin_amdgcn_mfma_f32_16x16x32_bf16(a0, b0f, acc[nt], 0, 0, 0);
    acc[nt] = __builtin_amdgcn_mfma_f32_16x16x32_bf16(a1, b1f, acc[nt], 0, 0, 0);
    acc[nt] = __builtin_amdgcn_mfma_f32_16x16x32_bf16(a2, b2f, acc[nt], 0, 0, 0);
  }

  const int tl0 = m0 + quad * 4;
  const int blb = tl0 / SEQ;
  const int ss0 = tl0 - blb * SEQ;

  if (n0 < NHEAD * HDIM) {
#pragma unroll
    for (int nt = 0; nt < 4; nt++) {
      int n = n0 + nt * 16 + tq;
      float bias = bk[n];
#pragma unroll
      for (int j = 0; j < 4; j++)
        tile[wave][quad * 4 + j][nt * 16 + tq] = f2bf(acc[nt][j] + bias);
    }
#pragma unroll
    for (int it = 0; it < 2; it++) {
      int idx = it * 64 + lane;
      int row = idx >> 3;
      int seg = idx & 7;
      int tl = m0 + row;
      int bb = tl / SEQ;
      int ss = tl - bb * SEQ;
      int r0s = n0 + seg * 8;
      int hh2 = r0s / HDIM;
      int d0 = r0s - hh2 * HDIM;
      bf16x8 v = *(const bf16x8*)&tile[wave][row][seg * 8];
      *(bf16x8*)((short*)kbuf +
                 ((size_t)(bb * NHEAD + hh2) * SEQ + ss) * HDIM + d0) = v;
    }
  } else {
#pragma unroll
    for (int nt = 0; nt < 4; nt++) {
      int n = n0 + nt * 16 + tq;
      int r = n - NHEAD * HDIM;
      int hh2 = r / HDIM;
      int d = r - hh2 * HDIM;
      float bias = bv[r];
      bf16x4 pack;
#pragma unroll
      for (int j = 0; j < 4; j++) pack[j] = f2bf(acc[nt][j] + bias);
      *(bf16x4*)((short*)vbufT +
                 ((size_t)(blb * NHEAD + hh2) * HDIM + d) * SEQ + ss0) = pack;
    }
  }
}

// ---------------- Kernel 3: flash attention, transposed softmax ------------
// Swapped MFMA operands: S^T = mfma(K,Q), O^T = mfma(V^T,P).
// Lane holds one q-row (q = lane&15): m/l are scalars, chunk-max is in-lane
// + 2 shuffles, rescale factors lane-local. P bounce: 8B packed writes.
// NARROW-WAVE/WIDE-BLOCK (round 6): 512-thread blocks, 8 waves x 16 q-rows.
// __launch_bounds__(512,4) -> 2 blocks/CU = 16 waves/CU (vs 9 before), while
// resident groups/XCD drops 19 -> ~13 (2.75MB < 4MB L2, safer than before).
// Per-wave regs ~80 << 128 cap. 8 waves issue identical K/V addrs -> L1
// (24KB chunk fits 32KB L1). 560%16==0 -> out-of-range waves early-return
// (no barriers in kernel -> safe), removing pad-row K/V streaming entirely.
// NOTE (round 4): register double-buffering K (48 VGPR) spills. Do not retry
// at 3 waves/EU. NOTE (round 5): setprio around MFMA clusters regressed ~4%
// (QK cluster contains the K loads; priority starves co-waves' loads). Out.
#define QW 104   // Q bounce row stride (shorts): 208B rows, 16B-aligned
#define PW32 36  // P bounce row stride (u32): 144B rows, 16B-aligned
__global__ __launch_bounds__(512, 4) void attn_flash_kernel(
    const __hip_bfloat16* __restrict__ hbf,
    const __hip_bfloat16* __restrict__ wqT, const float* __restrict__ bq,
    const __hip_bfloat16* __restrict__ kbuf,
    const __hip_bfloat16* __restrict__ vbufT,
    __hip_bfloat16* __restrict__ heads, int b0) {
  const int flat = blockIdx.x;
  const int xcd = flat & 7;
  const int slot = flat >> 3;
  const int g = (slot / 5) * 8 + xcd;  // 0..383 group = (bl,hh), XCD-local
  const int qt = slot % 5;             // 0..4, 128 q-rows per block
  const int hh = g % NHEAD;
  const int bl = g / NHEAD;            // local batch 0..31
  const int wave = threadIdx.x >> 6;   // 0..7
  const int lane = threadIdx.x & 63;
  const int tq = lane & 15;
  const int quad = lane >> 4;

  __shared__ __align__(16) short sbuf[8][1664];  // 26,624 B total
  short* pw = sbuf[wave];                        // wave-private 16xQW region
  unsigned int* pwA = (unsigned int*)pw;         // P: 16 x PW32 u32 (reuses Q)

  const int q0 = qt * 128 + wave * 16;
  if (q0 >= SEQ) return;  // pad waves (rows 560..639) exit; no barriers here

  const size_t bh = (size_t)(bl * NHEAD + hh);
  const short* kb = (const short*)kbuf + bh * SEQ * HDIM;
  const short* vb = (const short*)vbufT + bh * HDIM * SEQ;

  // ---- (1) Q projection via MFMA: one 16-row tile ----
  const int qr = q0 + tq;  // < SEQ guaranteed (560 % 16 == 0)
  const short* hp =
      (const short*)hbf + ((size_t)(b0 + bl) * SEQ + qr) * EMB + quad * 8;
  bf16x8 ha0 = *(const bf16x8*)(hp);
  bf16x8 ha1 = *(const bf16x8*)(hp + 32);
  bf16x8 ha2 = *(const bf16x8*)(hp + 64);
  const f32x4 zero4 = {0.f, 0.f, 0.f, 0.f};
  f32x4 qacc[6];
#pragma unroll
  for (int dt = 0; dt < 6; dt++) qacc[dt] = zero4;
#pragma unroll
  for (int dt = 0; dt < 6; dt++) {
    const short* wp = (const short*)wqT +
                      ((size_t)hh * HDIM + dt * 16 + tq) * EMB + quad * 8;
    bf16x8 w0 = *(const bf16x8*)(wp);
    bf16x8 w1 = *(const bf16x8*)(wp + 32);
    bf16x8 w2 = *(const bf16x8*)(wp + 64);
    qacc[dt] = __builtin_amdgcn_mfma_f32_16x16x32_bf16(ha0, w0, qacc[dt], 0, 0, 0);
    qacc[dt] = __builtin_amdgcn_mfma_f32_16x16x32_bf16(ha1, w1, qacc[dt], 0, 0, 0);
    qacc[dt] = __builtin_amdgcn_mfma_f32_16x16x32_bf16(ha2, w2, qacc[dt], 0, 0, 0);
  }
#pragma unroll
  for (int dt = 0; dt < 6; dt++) {
    int d = dt * 16 + tq;
    float bias = bq[hh * HDIM + d];
#pragma unroll
    for (int r = 0; r < 4; r++)
      pw[(quad * 4 + r) * QW + d] = f2bf((qacc[dt][r] + bias) * SCALE_L2E);
  }
  bf16x8 aq0 = *(const bf16x8*)&pw[tq * QW + quad * 8];
  bf16x8 aq1 = *(const bf16x8*)&pw[tq * QW + 32 + quad * 8];
  bf16x8 aq2 = *(const bf16x8*)&pw[tq * QW + 64 + quad * 8];
  // Q region dead once aq regs are loaded; pwA reuses it (same wave).

  // ---- (2) online-softmax main loop, transposed space -------------------
  // S^T tile layout: col = q = tq (lane-local), row = k = 16t + quad*4 + r.
  f32x4 o[6];  // O^T: col = q = tq, row = d = 16dt + quad*4 + r
#pragma unroll
  for (int dt = 0; dt < 6; dt++) o[dt] = zero4;
  float m = -1e30f, l = 0.f;

  for (int c = 0; c < 9; c++) {
    const int col0 = c * 64;
    f32x4 s[4];
#pragma unroll
    for (int t = 0; t < 4; t++) s[t] = zero4;
#pragma unroll
    for (int t = 0; t < 4; t++) {
      const short* kp = kb + (size_t)(col0 + t * 16 + tq) * HDIM + quad * 8;
      bf16x8 k0 = *(const bf16x8*)(kp);
      bf16x8 k1 = *(const bf16x8*)(kp + 32);
      bf16x8 k2 = *(const bf16x8*)(kp + 64);
      // swapped: A = K rows, B = Q rows -> C[row=k, col=q]
      s[t] = __builtin_amdgcn_mfma_f32_16x16x32_bf16(k0, aq0, s[t], 0, 0, 0);
      s[t] = __builtin_amdgcn_mfma_f32_16x16x32_bf16(k1, aq1, s[t], 0, 0, 0);
      s[t] = __builtin_amdgcn_mfma_f32_16x16x32_bf16(k2, aq2, s[t], 0, 0, 0);
    }
    if (c == 8) {  // k rows 560..575 out of range (tile t=3): mask
#pragma unroll
      for (int r = 0; r < 4; r++) s[3][r] = -1e30f;
    }
    // chunk max: in-lane over 16 k's, then across quads (2 shuffles)
    float cm = s[0][0];
#pragma unroll
    for (int t = 0; t < 4; t++) {
#pragma unroll
      for (int r = 0; r < 4; r++) cm = fmaxf(cm, s[t][r]);
    }
    cm = fmaxf(cm, __shfl_xor(cm, 16, 64));
    cm = fmaxf(cm, __shfl_xor(cm, 32, 64));
    // exact skip-rescale (lane-local scalars, wave-uniform branch)
    if (__any(cm > m)) {
      float mn = fmaxf(m, cm);
      float f = exp2_fast(m - mn);
      m = mn; l *= f;
#pragma unroll
      for (int dt = 0; dt < 6; dt++) {
#pragma unroll
        for (int r = 0; r < 4; r++) o[dt][r] *= f;
      }
    }
    // P = 2^(s-m); pack pairs; wave-private LDS bounce (row q=tq)
#pragma unroll
    for (int t = 0; t < 4; t++) {
      float p0 = exp2_fast(s[t][0] - m);
      float p1 = exp2_fast(s[t][1] - m);
      float p2 = exp2_fast(s[t][2] - m);
      float p3 = exp2_fast(s[t][3] - m);
      l += (p0 + p1) + (p2 + p3);
      u32x2 w = {pack2bf(p0, p1), pack2bf(p2, p3)};
      *(u32x2*)&pwA[tq * PW32 + t * 8 + quad * 2] = w;
    }
    // read P as B-fragments: lane holds P[q=tq, k=quad*8 ..+8 per half]
    bf16x8 pa0 = *(const bf16x8*)&pwA[tq * PW32 + quad * 4];
    bf16x8 pa1 = *(const bf16x8*)&pwA[tq * PW32 + 16 + quad * 4];
    // PV swapped: A = V^T rows (d), B = P rows (q) -> O^T[row=d, col=q]
#pragma unroll
    for (int dt = 0; dt < 6; dt++) {
      const short* vp = vb + (size_t)(dt * 16 + tq) * SEQ + col0 + quad * 8;
      bf16x8 v0 = *(const bf16x8*)(vp);
      bf16x8 v1 = *(const bf16x8*)(vp + 32);
      o[dt] = __builtin_amdgcn_mfma_f32_16x16x32_bf16(v0, pa0, o[dt], 0, 0, 0);
      o[dt] = __builtin_amdgcn_mfma_f32_16x16x32_bf16(v1, pa1, o[dt], 0, 0, 0);
    }
  }

  // ---- (3) finalize: cross-quad l reduce, normalize, packed stores ----
  l += __shfl_xor(l, 16, 64);
  l += __shfl_xor(l, 32, 64);
  float rcp = 1.f / l;
  short* hpout = (short*)heads +
                 ((size_t)(b0 + bl) * SEQ + q0 + tq) * (NHEAD * HDIM) +
                 hh * HDIM;
#pragma unroll
  for (int dt = 0; dt < 6; dt++) {
    bf16x4 pk;
#pragma unroll
    for (int r = 0; r < 4; r++) pk[r] = f2bf(o[dt][r] * rcp);
    *(bf16x4*)(hpout + dt * 16 + quad * 4) = pk;
  }
}

// ---------------- Kernel 4: Wo GEMM + residual + LayerNorm (MFMA, proven) --
__global__ __launch_bounds__(256) void wo_ln_mfma_kernel(
    const __hip_bfloat16* __restrict__ heads,
    const __hip_bfloat16* __restrict__ woT, const float* __restrict__ bo,
    const float* __restrict__ gamma, const float* __restrict__ beta,
    const float* __restrict__ hres, float* __restrict__ hA,
    __hip_bfloat16* __restrict__ hbf) {
  const int wave = threadIdx.x >> 6;
  const int lane = threadIdx.x & 63;
  const int tq = lane & 15;
  const int quad = lane >> 4;
  const int m0 = blockIdx.x * 64 + wave * 16;

  const short* ap = (const short*)heads + (size_t)(m0 + tq) * (NHEAD * HDIM);
  const short* bp = (const short*)woT;

  f32x4 acc[6];
  const f32x4 zero4 = {0.f, 0.f, 0.f, 0.f};
#pragma unroll
  for (int dt = 0; dt < 6; dt++) acc[dt] = zero4;

  for (int kt = 0; kt < 36; kt++) {
    bf16x8 af = *(const bf16x8*)(ap + kt * 32 + quad * 8);
#pragma unroll
    for (int dt = 0; dt < 6; dt++) {
      bf16x8 bfr = *(const bf16x8*)(bp + (size_t)(dt * 16 + tq) * (NHEAD * HDIM) +
                                    kt * 32 + quad * 8);
      acc[dt] = __builtin_amdgcn_mfma_f32_16x16x32_bf16(af, bfr, acc[dt], 0, 0, 0);
    }
  }

  const int tok0 = m0 + quad * 4;
  float s1[4] = {0.f, 0.f, 0.f, 0.f};
  float s2[4] = {0.f, 0.f, 0.f, 0.f};
#pragma unroll
  for (int dt = 0; dt < 6; dt++) {
    int n = dt * 16 + tq;
    float bias = bo[n];
#pragma unroll
    for (int r = 0; r < 4; r++) {
      float val = acc[dt][r] + bias + hres[(size_t)(tok0 + r) * EMB + n];
      acc[dt][r] = val;
      s1[r] += val;
      s2[r] += val * val;
    }
  }
#pragma unroll
  for (int mask = 1; mask < 16; mask <<= 1) {
#pragma unroll
    for (int r = 0; r < 4; r++) {
      s1[r] += __shfl_xor(s1[r], mask, 64);
      s2[r] += __shfl_xor(s2[r], mask, 64);
    }
  }
  float mean[4], rstd[4];
#pragma unroll
  for (int r = 0; r < 4; r++) {
    mean[r] = s1[r] * (1.0f / EMB);
    float var = s2[r] * (1.0f / EMB) - mean[r] * mean[r];
    rstd[r] = rsqrtf(var + EPSV);
  }
#pragma unroll
  for (int dt = 0; dt < 6; dt++) {
    int n = dt * 16 + tq;
    float g = gamma[n], bt = beta[n];
#pragma unroll
    for (int r = 0; r < 4; r++) {
      float o = (acc[dt][r] - mean[r]) * rstd[r] * g + bt;
      hA[(size_t)(tok0 + r) * EMB + n] = o;
      hbf[(size_t)(tok0 + r) * EMB + n] = __float2bfloat16(o);
    }
  }
}

// ---------------- Kernel 5: FF1 GEMM + ReLU (MFMA, proven) -----------------
__global__ __launch_bounds__(256) void ff1_mfma_kernel(
    const __hip_bfloat16* __restrict__ hbf,
    const __hip_bfloat16* __restrict__ ff1WT, const float* __restrict__ b1,
    __hip_bfloat16* __restrict__ ffbf) {
  const int wave = threadIdx.x >> 6;
  const int lane = threadIdx.x & 63;
  const int tq = lane & 15;
  const int quad = lane >> 4;
  const int m0 = blockIdx.x * 64 + wave * 16;

  const short* ap = (const short*)hbf + (size_t)(m0 + tq) * EMB + quad * 8;
  bf16x8 a0 = *(const bf16x8*)(ap);
  bf16x8 a1 = *(const bf16x8*)(ap + 32);
  bf16x8 a2 = *(const bf16x8*)(ap + 64);

  f32x4 acc[16];
  const f32x4 zero4 = {0.f, 0.f, 0.f, 0.f};
#pragma unroll
  for (int nt = 0; nt < 16; nt++) acc[nt] = zero4;
#pragma unroll
  for (int nt = 0; nt < 16; nt++) {
    const short* bp =
        (const short*)ff1WT + (size_t)(nt * 16 + tq) * EMB + quad * 8;
    bf16x8 b0f = *(const bf16x8*)(bp);
    bf16x8 b1f = *(const bf16x8*)(bp + 32);
    bf16x8 b2f = *(const bf16x8*)(bp + 64);
    acc[nt] = __builtin_amdgcn_mfma_f32_16x16x32_bf16(a0, b0f, acc[nt], 0, 0, 0);
    acc[nt] = __builtin_amdgcn_mfma_f32_16x16x32_bf16(a1, b1f, acc[nt], 0, 0, 0);
    acc[nt] = __builtin_amdgcn_mfma_f32_16x16x32_bf16(a2, b2f, acc[nt], 0, 0, 0);
  }

  const int tok0 = m0 + quad * 4;
#pragma unroll
  for (int nt = 0; nt < 16; nt++) {
    int n = nt * 16 + tq;
    float bias = b1[n];
#pragma unroll
    for (int r = 0; r < 4; r++) {
      ffbf[(size_t)(tok0 + r) * FFDIM + n] =
          __float2bfloat16(fmaxf(acc[nt][r] + bias, 0.f));
    }
  }
}

// ---------------- Kernel 6: FF2 GEMM + residual + LN (MFMA, proven) --------
__global__ __launch_bounds__(256) void ff2_ln_mfma_kernel(
    const __hip_bfloat16* __restrict__ ffbf,
    const __hip_bfloat16* __restrict__ ff2WT, const float* __restrict__ b2,
    const float* __restrict__ gamma, const float* __restrict__ beta,
    const float* __restrict__ hres, float* __restrict__ hout,
    __hip_bfloat16* __restrict__ hbf_out) {
  const int wave = threadIdx.x >> 6;
  const int lane = threadIdx.x & 63;
  const int tq = lane & 15;
  const int quad = lane >> 4;
  const int m0 = blockIdx.x * 64 + wave * 16;

  const short* ap = (const short*)ffbf + (size_t)(m0 + tq) * FFDIM;
  const short* bp = (const short*)ff2WT;

  f32x4 acc[6];
  const f32x4 zero4 = {0.f, 0.f, 0.f, 0.f};
#pragma unroll
  for (int dt = 0; dt < 6; dt++) acc[dt] = zero4;

#pragma unroll
  for (int kt = 0; kt < 8; kt++) {
    bf16x8 af = *(const bf16x8*)(ap + kt * 32 + quad * 8);
#pragma unroll
    for (int dt = 0; dt < 6; dt++) {
      bf16x8 bfr = *(const bf16x8*)(bp + (size_t)(dt * 16 + tq) * FFDIM +
                                    kt * 32 + quad * 8);
      acc[dt] = __builtin_amdgcn_mfma_f32_16x16x32_bf16(af, bfr, acc[dt], 0, 0, 0);
    }
  }

  const int tok0 = m0 + quad * 4;
  float s1[4] = {0.f, 0.f, 0.f, 0.f};
  float s2[4] = {0.f, 0.f, 0.f, 0.f};
#pragma unroll
  for (int dt = 0; dt < 6; dt++) {
    int n = dt * 16 + tq;
    float bias = b2[n];
#pragma unroll
    for (int r = 0; r < 4; r++) {
      float val = acc[dt][r] + bias + hres[(size_t)(tok0 + r) * EMB + n];
      acc[dt][r] = val;
      s1[r] += val;
      s2[r] += val * val;
    }
  }
#pragma unroll
  for (int mask = 1; mask < 16; mask <<= 1) {
#pragma unroll
    for (int r = 0; r < 4; r++) {
      s1[r] += __shfl_xor(s1[r], mask, 64);
      s2[r] += __shfl_xor(s2[r], mask, 64);
    }
  }
  float mean[4], rstd[4];
#pragma unroll
  for (int r = 0; r < 4; r++) {
    mean[r] = s1[r] * (1.0f / EMB);
    float var = s2[r] * (1.0f / EMB) - mean[r] * mean[r];
    rstd[r] = rsqrtf(var + EPSV);
  }
#pragma unroll
  for (int dt = 0; dt < 6; dt++) {
    int n = dt * 16 + tq;
    float g = gamma[n], bt = beta[n];
#pragma unroll
    for (int r = 0; r < 4; r++) {
      float o = (acc[dt][r] - mean[r]) * rstd[r] * g + bt;
      hout[(size_t)(tok0 + r) * EMB + n] = o;
      hbf_out[(size_t)(tok0 + r) * EMB + n] = __float2bfloat16(o);
    }
  }
}

// ---------------- launch ----------------------------------------------------
extern "C" void kernel_launch(void* const* d_in, const int* in_sizes, int n_in,
                              void* d_out, int out_size, void* d_ws,
                              size_t ws_size, hipStream_t stream) {
  const float* x = (const float*)d_in[0];
  const float* patch_W = (const float*)d_in[1];
  const float* patch_b = (const float*)d_in[2];
  const float* Wq = (const float*)d_in[3];
  const float* bq = (const float*)d_in[4];
  const float* Wk = (const float*)d_in[5];
  const float* bk = (const float*)d_in[6];
  const float* Wv = (const float*)d_in[7];
  const float* bv = (const float*)d_in[8];
  const float* Wo = (const float*)d_in[9];
  const float* bo = (const float*)d_in[10];
  const float* ff1_W = (const float*)d_in[11];
  const float* ff1_b = (const float*)d_in[12];
  const float* ff2_W = (const float*)d_in[13];
  const float* ff2_b = (const float*)d_in[14];
  const float* n1_g = (const float*)d_in[15];
  const float* n1_b = (const float*)d_in[16];
  const float* n2_g = (const float*)d_in[17];
  const float* n2_b = (const float*)d_in[18];

  // workspace layout (~202 MB)
  const size_t h_bytes = (size_t)TOK * EMB * sizeof(float);          // 13.76 MB
  const size_t hbf_bytes = (size_t)TOK * EMB * 2;                    // 6.88 MB
  const size_t kv_bytes = (size_t)CHUNK * NHEAD * SEQ * HDIM * 2;    // 41.29 MB
  const size_t heads_bytes = (size_t)TOK * NHEAD * HDIM * 2;         // 82.58 MB
  const size_t wqT_bytes = (size_t)NLAYER * NHEAD * HDIM * EMB * 2;  // 0.44 MB
  const size_t wkvT_bytes = 2 * wqT_bytes;                           // 0.88 MB
  const size_t woT_bytes = (size_t)NLAYER * EMB * NHEAD * HDIM * 2;  // 0.44 MB
  const size_t ffw_bytes = (size_t)NLAYER * FFDIM * EMB * 2;         // 0.10 MB
  char* ws = (char*)d_ws;
  size_t off = 0;
  float* h = (float*)(ws + off); off += h_bytes;
  float* hA = (float*)(ws + off); off += h_bytes;
  __hip_bfloat16* hbf = (__hip_bfloat16*)(ws + off); off += hbf_bytes;
  __hip_bfloat16* kbuf = (__hip_bfloat16*)(ws + off); off += kv_bytes;
  __hip_bfloat16* vbufT = (__hip_bfloat16*)(ws + off); off += kv_bytes;
  __hip_bfloat16* heads = (__hip_bfloat16*)(ws + off); off += heads_bytes;
  __hip_bfloat16* wqT = (__hip_bfloat16*)(ws + off); off += wqT_bytes;
  __hip_bfloat16* wkvT = (__hip_bfloat16*)(ws + off); off += wkvT_bytes;
  __hip_bfloat16* woT = (__hip_bfloat16*)(ws + off); off += woT_bytes;
  __hip_bfloat16* ff1WT = (__hip_bfloat16*)(ws + off); off += ffw_bytes;
  __hip_bfloat16* ff2WT = (__hip_bfloat16*)(ws + off); off += ffw_bytes;
  __hip_bfloat16* ffbf = (__hip_bfloat16*)kbuf;  // alias: free after attention

  allprep_kernel<<<78, 256, 0, stream>>>(Wq, Wk, Wv, Wo, ff1_W, ff2_W, wqT,
                                         wkvT, woT, ff1WT, ff2WT);
  patch_pe_kernel<<<(TOK * EMB + 255) / 256, 256, 0, stream>>>(x, patch_W,
                                                               patch_b, h, hbf);

  for (int l = 0; l < NLAYER; l++) {
    const __hip_bfloat16* wqT_l = wqT + (size_t)l * NHEAD * HDIM * EMB;
    const __hip_bfloat16* wkvT_l = wkvT + (size_t)l * 2 * NHEAD * HDIM * EMB;
    const __hip_bfloat16* woT_l = woT + (size_t)l * EMB * NHEAD * HDIM;
    const __hip_bfloat16* ff1WT_l = ff1WT + (size_t)l * FFDIM * EMB;
    const __hip_bfloat16* ff2WT_l = ff2WT + (size_t)l * EMB * FFDIM;
    const float* bq_l = bq + (size_t)l * NHEAD * HDIM;
    const float* bk_l = bk + (size_t)l * NHEAD * HDIM;
    const float* bv_l = bv + (size_t)l * NHEAD * HDIM;
    const float* bo_l = bo + (size_t)l * EMB;

    for (int c = 0; c < BATCH / CHUNK; c++) {
      int b0 = c * CHUNK;
      kv_mfma_kernel<<<dim3(CHUNK * SEQ / 64, 2 * NHEAD * HDIM / 64), 256, 0,
                       stream>>>(hbf, wkvT_l, bk_l, bv_l, kbuf, vbufT, b0);
      // 5 q-blocks (128 rows each) x 384 (bl,hh) groups, XCD-swizzled;
      // 512-thread blocks: 8 waves x 16 q-rows
      attn_flash_kernel<<<5 * NHEAD * CHUNK, 512, 0, stream>>>(
          hbf, wqT_l, bq_l, kbuf, vbufT, heads, b0);
    }
    // LN1: reads residual h, writes hA (fp32) + hbf (bf16)
    wo_ln_mfma_kernel<<<TOK / 64, 256, 0, stream>>>(
        heads, woT_l, bo_l, n1_g + l * EMB, n1_b + l * EMB, h, hA, hbf);
    // FF path (MFMA, split, proven): ff1 reads hbf -> ffbf; ff2 reads ffbf + hA
    ff1_mfma_kernel<<<TOK / 64, 256, 0, stream>>>(hbf, ff1WT_l,
                                                  ff1_b + l * FFDIM, ffbf);
    float* dst = (l == NLAYER - 1) ? (float*)d_out : h;
    ff2_ln_mfma_kernel<<<TOK / 64, 256, 0, stream>>>(
        ffbf, ff2WT_l, ff2_b + l * EMB, n2_g + l * EMB, n2_b + l * EMB, hA,
        dst, hbf);
  }
}

// Round 8
// 1191.811 us; speedup vs baseline: 1.2271x; 1.2271x over previous
//
#include <hip/hip_runtime.h>
#include <hip/hip_bf16.h>
#include <math.h>

#define BATCH 64
#define INPUT_SIZE 10080
#define PATCH 18
#define SEQ 560            // S
#define EMB 96             // E
#define NHEAD 12           // H
#define HDIM 96            // D
#define FFDIM 256          // F
#define NLAYER 2
#define TOK (BATCH * SEQ)  // 35840 tokens
#define EPSV 1e-5f
#define SCALE 0.10206207261596577f      // 1/sqrt(96)
#define SCALE_L2E 0.14724443805513492f  // SCALE * log2(e): scores in log2 space

typedef __attribute__((ext_vector_type(8))) short bf16x8;  // 8 bf16 (4 VGPRs)
typedef __attribute__((ext_vector_type(4))) short bf16x4;  // 4 bf16 (8B store)
typedef __attribute__((ext_vector_type(4))) float f32x4;   // 4 fp32 acc
typedef __attribute__((ext_vector_type(2))) unsigned int u32x2;

static __device__ __forceinline__ short f2bf(float x) {
  union { __hip_bfloat16 b; short s; } u;
  u.b = __float2bfloat16(x);
  return u.s;
}

// pack two floats as 2 bf16 in one u32 (lo in low half)
static __device__ __forceinline__ unsigned int pack2bf(float lo, float hi) {
  unsigned int a = (unsigned short)f2bf(lo);
  unsigned int b = (unsigned short)f2bf(hi);
  return a | (b << 16);
}

// raw v_exp_f32: 2^x (scores are pre-scaled by log2(e))
static __device__ __forceinline__ float exp2_fast(float x) {
  float r;
  asm("v_exp_f32 %0, %1" : "=v"(r) : "v"(x));
  return r;
}

// ---------------- Kernel 0: all weight transposes, one launch --------------
__global__ __launch_bounds__(256) void allprep_kernel(
    const float* __restrict__ Wq, const float* __restrict__ Wk,
    const float* __restrict__ Wv, const float* __restrict__ Wo,
    const float* __restrict__ ff1_W, const float* __restrict__ ff2_W,
    __hip_bfloat16* __restrict__ wqT, __hip_bfloat16* __restrict__ wkvT,
    __hip_bfloat16* __restrict__ woT, __hip_bfloat16* __restrict__ ff1WT,
    __hip_bfloat16* __restrict__ ff2WT) {
  int bx = blockIdx.x;
  if (bx < 72) {
    int hh = bx % NHEAD, mat = (bx / NHEAD) % 3, l = bx / 36;
    const float* src = (mat == 0 ? Wq : (mat == 1 ? Wk : Wv)) +
                       ((size_t)l * NHEAD + hh) * EMB * HDIM;
    __shared__ float t[HDIM * 97];
    for (int i = threadIdx.x; i < EMB * HDIM; i += 256) {
      int e = i / HDIM, d = i % HDIM;
      t[d * 97 + e] = src[i];
    }
    __syncthreads();
    __hip_bfloat16* dst;
    if (mat == 0)
      dst = wqT + ((size_t)l * NHEAD + hh) * HDIM * EMB;
    else
      dst = wkvT + ((size_t)l * 2 * NHEAD * HDIM + (mat - 1) * NHEAD * HDIM +
                    hh * HDIM) * EMB;
    for (int j = threadIdx.x; j < HDIM * EMB; j += 256) {
      int d = j / EMB, e = j % EMB;
      dst[j] = __float2bfloat16(t[d * 97 + e]);
    }
  } else if (bx < 74) {
    int l = bx - 72;
    const float* src = Wo + (size_t)l * NHEAD * HDIM * EMB;
    __hip_bfloat16* dst = woT + (size_t)l * EMB * NHEAD * HDIM;
    for (int i = threadIdx.x; i < EMB * NHEAD * HDIM; i += 256) {
      int e = i / (NHEAD * HDIM), j = i % (NHEAD * HDIM);
      dst[i] = __float2bfloat16(src[(size_t)j * EMB + e]);
    }
  } else {
    int idx = bx - 74;
    int mat = idx % 2, l = idx / 2;
    if (mat == 0) {
      const float* src = ff1_W + (size_t)l * EMB * FFDIM;
      __hip_bfloat16* dst = ff1WT + (size_t)l * FFDIM * EMB;
      for (int i = threadIdx.x; i < FFDIM * EMB; i += 256) {
        int f = i / EMB, e = i % EMB;
        dst[i] = __float2bfloat16(src[(size_t)e * FFDIM + f]);
      }
    } else {
      const float* src = ff2_W + (size_t)l * FFDIM * EMB;
      __hip_bfloat16* dst = ff2WT + (size_t)l * EMB * FFDIM;
      for (int i = threadIdx.x; i < EMB * FFDIM; i += 256) {
        int e = i / FFDIM, f = i % FFDIM;
        dst[i] = __float2bfloat16(src[(size_t)f * EMB + e]);
      }
    }
  }
}

// ---------------- Kernel 1: patch embedding + sinusoidal PE ----------------
__global__ void patch_pe_kernel(const float* __restrict__ x,
                                const float* __restrict__ W,
                                const float* __restrict__ bias,
                                float* __restrict__ h,
                                __hip_bfloat16* __restrict__ hbf) {
  int gid = blockIdx.x * blockDim.x + threadIdx.x;
  if (gid >= TOK * EMB) return;
  int tok = gid / EMB;
  int e = gid % EMB;
  int b = tok / SEQ;
  int s = tok % SEQ;
  const float* xp = x + b * INPUT_SIZE + s * PATCH;
  float acc = bias[e];
#pragma unroll
  for (int p = 0; p < PATCH; p++) acc += xp[p] * W[p * EMB + e];
  int i = e >> 1;
  float freq = __expf(-(float)(2 * i) * (9.210340371976184f / 96.0f));
  float ang = (float)s * freq;
  acc += (e & 1) ? cosf(ang) : sinf(ang);
  h[gid] = acc;
  hbf[gid] = __float2bfloat16(acc);
}

// ---------------- Kernel 2: K/V projection GEMM (MFMA) ---------------------
// Works for any batch-chunk size: m0 spans [0, chunk*SEQ) via gridDim.x.
__global__ __launch_bounds__(256) void kv_mfma_kernel(
    const __hip_bfloat16* __restrict__ hbf,
    const __hip_bfloat16* __restrict__ wkvT, const float* __restrict__ bk,
    const float* __restrict__ bv, __hip_bfloat16* __restrict__ kbuf,
    __hip_bfloat16* __restrict__ vbufT, int b0) {
  const int wave = threadIdx.x >> 6;
  const int lane = threadIdx.x & 63;
  const int tq = lane & 15;
  const int quad = lane >> 4;
  const int m0 = blockIdx.x * 64 + wave * 16;  // token tile row (chunk-local)
  const int n0 = blockIdx.y * 64;

  __shared__ short tile[4][16][68];  // wave-local K bounce (8.7 KB)

  const short* ap =
      (const short*)hbf + ((size_t)b0 * SEQ + m0 + tq) * EMB + quad * 8;
  bf16x8 a0 = *(const bf16x8*)(ap);
  bf16x8 a1 = *(const bf16x8*)(ap + 32);
  bf16x8 a2 = *(const bf16x8*)(ap + 64);

  f32x4 acc[4];
  const f32x4 zero4 = {0.f, 0.f, 0.f, 0.f};
#pragma unroll
  for (int nt = 0; nt < 4; nt++) acc[nt] = zero4;
#pragma unroll
  for (int nt = 0; nt < 4; nt++) {
    const short* bp =
        (const short*)wkvT + (size_t)(n0 + nt * 16 + tq) * EMB + quad * 8;
    bf16x8 b0f = *(const bf16x8*)(bp);
    bf16x8 b1f = *(const bf16x8*)(bp + 32);
    bf16x8 b2f = *(const bf16x8*)(bp + 64);
    acc[nt] = __builtin_amdgcn_mfma_f32_16x16x32_bf16(a0, b0f, acc[nt], 0, 0, 0);
    acc[nt] = __builtin_amdgcn_mfma_f32_16x16x32_bf16(a1, b1f, acc[nt], 0, 0, 0);
    acc[nt] = __builtin_amdgcn_mfma_f32_16x16x32_bf16(a2, b2f, acc[nt], 0, 0, 0);
  }

  const int tl0 = m0 + quad * 4;
  const int blb = tl0 / SEQ;
  const int ss0 = tl0 - blb * SEQ;

  if (n0 < NHEAD * HDIM) {
#pragma unroll
    for (int nt = 0; nt < 4; nt++) {
      int n = n0 + nt * 16 + tq;
      float bias = bk[n];
#pragma unroll
      for (int j = 0; j < 4; j++)
        tile[wave][quad * 4 + j][nt * 16 + tq] = f2bf(acc[nt][j] + bias);
    }
#pragma unroll
    for (int it = 0; it < 2; it++) {
      int idx = it * 64 + lane;
      int row = idx >> 3;
      int seg = idx & 7;
      int tl = m0 + row;
      int bb = tl / SEQ;
      int ss = tl - bb * SEQ;
      int r0s = n0 + seg * 8;
      int hh2 = r0s / HDIM;
      int d0 = r0s - hh2 * HDIM;
      bf16x8 v = *(const bf16x8*)&tile[wave][row][seg * 8];
      *(bf16x8*)((short*)kbuf +
                 ((size_t)(bb * NHEAD + hh2) * SEQ + ss) * HDIM + d0) = v;
    }
  } else {
#pragma unroll
    for (int nt = 0; nt < 4; nt++) {
      int n = n0 + nt * 16 + tq;
      int r = n - NHEAD * HDIM;
      int hh2 = r / HDIM;
      int d = r - hh2 * HDIM;
      float bias = bv[r];
      bf16x4 pack;
#pragma unroll
      for (int j = 0; j < 4; j++) pack[j] = f2bf(acc[nt][j] + bias);
      *(bf16x4*)((short*)vbufT +
                 ((size_t)(blb * NHEAD + hh2) * HDIM + d) * SEQ + ss0) = pack;
    }
  }
}

// ---------------- Kernel 3: flash attention, transposed softmax ------------
// (round-3 proven structure, byte-identical: 158 us/1920-block launch)
// Swapped MFMA operands: S^T = mfma(K,Q), O^T = mfma(V^T,P).
// Lane holds one q-row (q = lane&15): m/l are scalars, chunk-max is in-lane
// + 2 shuffles, rescale factors lane-local. P bounce: 8B packed writes.
// __launch_bounds__(256,3): keeps co-resident groups/XCD * 215KB panel under
// the 4MB L2 (bounds(256,4) thrashed L2: FETCH 58->195MB, dur +28%).
// FAILED variants (do not retry): K reg-double-buffer (r4: +48 VGPR > 170
// combined budget -> scratch spill, WRITE 40->380MB); setprio around MFMA
// (r5: -4%, QK cluster contains K loads); 512-thr 16-row waves (r7: 2x VMEM
// issue per row, occupancy stuck 32% -> 158->233us). Combined reg usage is
// ~155/170 at 3 waves/EU: NO headroom for any +24/+48-reg prefetch.
#define QW 104   // Q bounce row stride (shorts): 208B rows, 16B-aligned
#define PW32 36  // P bounce row stride (u32): 144B rows, 16B-aligned
__global__ __launch_bounds__(256, 3) void attn_flash_kernel(
    const __hip_bfloat16* __restrict__ hbf,
    const __hip_bfloat16* __restrict__ wqT, const float* __restrict__ bq,
    const __hip_bfloat16* __restrict__ kbuf,
    const __hip_bfloat16* __restrict__ vbufT,
    __hip_bfloat16* __restrict__ heads, int b0) {
  const int flat = blockIdx.x;
  const int xcd = flat & 7;
  const int slot = flat >> 3;
  const int g = (slot / 5) * 8 + xcd;  // group = (bl,hh), XCD-local
  const int qt = slot % 5;             // 0..4, 128 q-rows per block
  const int hh = g % NHEAD;
  const int bl = g / NHEAD;            // chunk-local batch
  const int wave = threadIdx.x >> 6;
  const int lane = threadIdx.x & 63;
  const int tq = lane & 15;
  const int quad = lane >> 4;

  __shared__ __align__(16) short sbuf[4][3328];  // 26,624 B total
  short* pw = sbuf[wave];                        // wave-private region
  unsigned int* pwA = (unsigned int*)pw;         // P set A: 16 x PW32 u32
  unsigned int* pwB = pwA + 16 * PW32;           // P set B: 16 x PW32 u32

  const size_t bh = (size_t)(bl * NHEAD + hh);
  const short* kb = (const short*)kbuf + bh * SEQ * HDIM;
  const short* vb = (const short*)vbufT + bh * HDIM * SEQ;

  const int q0 = qt * 128 + wave * 32;

  // ---- (1) Q projection via MFMA for two 16-row tiles ----
  int qrA = q0 + tq;      if (qrA > SEQ - 1) qrA = SEQ - 1;
  int qrB = q0 + 16 + tq; if (qrB > SEQ - 1) qrB = SEQ - 1;
  const short* hpA =
      (const short*)hbf + ((size_t)(b0 + bl) * SEQ + qrA) * EMB + quad * 8;
  const short* hpB =
      (const short*)hbf + ((size_t)(b0 + bl) * SEQ + qrB) * EMB + quad * 8;
  bf16x8 haA0 = *(const bf16x8*)(hpA);
  bf16x8 haA1 = *(const bf16x8*)(hpA + 32);
  bf16x8 haA2 = *(const bf16x8*)(hpA + 64);
  bf16x8 haB0 = *(const bf16x8*)(hpB);
  bf16x8 haB1 = *(const bf16x8*)(hpB + 32);
  bf16x8 haB2 = *(const bf16x8*)(hpB + 64);
  const f32x4 zero4 = {0.f, 0.f, 0.f, 0.f};
  f32x4 qaccA[6], qaccB[6];
#pragma unroll
  for (int dt = 0; dt < 6; dt++) { qaccA[dt] = zero4; qaccB[dt] = zero4; }
#pragma unroll
  for (int dt = 0; dt < 6; dt++) {
    const short* wp = (const short*)wqT +
                      ((size_t)hh * HDIM + dt * 16 + tq) * EMB + quad * 8;
    bf16x8 w0 = *(const bf16x8*)(wp);
    bf16x8 w1 = *(const bf16x8*)(wp + 32);
    bf16x8 w2 = *(const bf16x8*)(wp + 64);
    qaccA[dt] = __builtin_amdgcn_mfma_f32_16x16x32_bf16(haA0, w0, qaccA[dt], 0, 0, 0);
    qaccA[dt] = __builtin_amdgcn_mfma_f32_16x16x32_bf16(haA1, w1, qaccA[dt], 0, 0, 0);
    qaccA[dt] = __builtin_amdgcn_mfma_f32_16x16x32_bf16(haA2, w2, qaccA[dt], 0, 0, 0);
    qaccB[dt] = __builtin_amdgcn_mfma_f32_16x16x32_bf16(haB0, w0, qaccB[dt], 0, 0, 0);
    qaccB[dt] = __builtin_amdgcn_mfma_f32_16x16x32_bf16(haB1, w1, qaccB[dt], 0, 0, 0);
    qaccB[dt] = __builtin_amdgcn_mfma_f32_16x16x32_bf16(haB2, w2, qaccB[dt], 0, 0, 0);
  }
#pragma unroll
  for (int dt = 0; dt < 6; dt++) {
    int d = dt * 16 + tq;
    float bias = bq[hh * HDIM + d];
#pragma unroll
    for (int r = 0; r < 4; r++) {
      pw[(quad * 4 + r) * QW + d] = f2bf((qaccA[dt][r] + bias) * SCALE_L2E);
      pw[(16 + quad * 4 + r) * QW + d] = f2bf((qaccB[dt][r] + bias) * SCALE_L2E);
    }
  }
  bf16x8 aqA0 = *(const bf16x8*)&pw[tq * QW + quad * 8];
  bf16x8 aqA1 = *(const bf16x8*)&pw[tq * QW + 32 + quad * 8];
  bf16x8 aqA2 = *(const bf16x8*)&pw[tq * QW + 64 + quad * 8];
  bf16x8 aqB0 = *(const bf16x8*)&pw[(16 + tq) * QW + quad * 8];
  bf16x8 aqB1 = *(const bf16x8*)&pw[(16 + tq) * QW + 32 + quad * 8];
  bf16x8 aqB2 = *(const bf16x8*)&pw[(16 + tq) * QW + 64 + quad * 8];
  // Q region dead once aq regs are loaded; pwA/pwB reuse it (same wave).

  // ---- (2) online-softmax main loop, transposed space -------------------
  // S^T tile layout: col = q = tq (lane-local), row = k = 16t + quad*4 + r.
  f32x4 oA[6], oB[6];  // O^T: col = q = tq, row = d = 16dt + quad*4 + r
#pragma unroll
  for (int dt = 0; dt < 6; dt++) { oA[dt] = zero4; oB[dt] = zero4; }
  float mA = -1e30f, mB = -1e30f, lA = 0.f, lB = 0.f;

  for (int c = 0; c < 9; c++) {
    const int col0 = c * 64;
    f32x4 sA[4], sB[4];
#pragma unroll
    for (int t = 0; t < 4; t++) { sA[t] = zero4; sB[t] = zero4; }
#pragma unroll
    for (int t = 0; t < 4; t++) {
      const short* kp = kb + (size_t)(col0 + t * 16 + tq) * HDIM + quad * 8;
      bf16x8 k0 = *(const bf16x8*)(kp);
      bf16x8 k1 = *(const bf16x8*)(kp + 32);
      bf16x8 k2 = *(const bf16x8*)(kp + 64);
      // swapped: A = K rows, B = Q rows -> C[row=k, col=q]
      sA[t] = __builtin_amdgcn_mfma_f32_16x16x32_bf16(k0, aqA0, sA[t], 0, 0, 0);
      sA[t] = __builtin_amdgcn_mfma_f32_16x16x32_bf16(k1, aqA1, sA[t], 0, 0, 0);
      sA[t] = __builtin_amdgcn_mfma_f32_16x16x32_bf16(k2, aqA2, sA[t], 0, 0, 0);
      sB[t] = __builtin_amdgcn_mfma_f32_16x16x32_bf16(k0, aqB0, sB[t], 0, 0, 0);
      sB[t] = __builtin_amdgcn_mfma_f32_16x16x32_bf16(k1, aqB1, sB[t], 0, 0, 0);
      sB[t] = __builtin_amdgcn_mfma_f32_16x16x32_bf16(k2, aqB2, sB[t], 0, 0, 0);
    }
    if (c == 8) {  // k rows 560..575 out of range (tile t=3): mask
#pragma unroll
      for (int r = 0; r < 4; r++) { sA[3][r] = -1e30f; sB[3][r] = -1e30f; }
    }
    // chunk max: in-lane over 16 k's, then across quads (2 shuffles)
    float cA = sA[0][0], cB = sB[0][0];
#pragma unroll
    for (int t = 0; t < 4; t++) {
#pragma unroll
      for (int r = 0; r < 4; r++) {
        cA = fmaxf(cA, sA[t][r]);
        cB = fmaxf(cB, sB[t][r]);
      }
    }
    cA = fmaxf(cA, __shfl_xor(cA, 16, 64));
    cA = fmaxf(cA, __shfl_xor(cA, 32, 64));
    cB = fmaxf(cB, __shfl_xor(cB, 16, 64));
    cB = fmaxf(cB, __shfl_xor(cB, 32, 64));
    // exact skip-rescale (lane-local scalars, wave-uniform branch)
    if (__any((cA > mA) | (cB > mB))) {
      float mnA = fmaxf(mA, cA);
      float fA = exp2_fast(mA - mnA);
      mA = mnA; lA *= fA;
      float mnB = fmaxf(mB, cB);
      float fB = exp2_fast(mB - mnB);
      mB = mnB; lB *= fB;
#pragma unroll
      for (int dt = 0; dt < 6; dt++) {
#pragma unroll
        for (int r = 0; r < 4; r++) { oA[dt][r] *= fA; oB[dt][r] *= fB; }
      }
    }
    // P = 2^(s-m); pack pairs; wave-private LDS bounce (row q=tq)
#pragma unroll
    for (int t = 0; t < 4; t++) {
      float pA0 = exp2_fast(sA[t][0] - mA);
      float pA1 = exp2_fast(sA[t][1] - mA);
      float pA2 = exp2_fast(sA[t][2] - mA);
      float pA3 = exp2_fast(sA[t][3] - mA);
      lA += (pA0 + pA1) + (pA2 + pA3);
      u32x2 wA = {pack2bf(pA0, pA1), pack2bf(pA2, pA3)};
      *(u32x2*)&pwA[tq * PW32 + t * 8 + quad * 2] = wA;
      float pB0 = exp2_fast(sB[t][0] - mB);
      float pB1 = exp2_fast(sB[t][1] - mB);
      float pB2 = exp2_fast(sB[t][2] - mB);
      float pB3 = exp2_fast(sB[t][3] - mB);
      lB += (pB0 + pB1) + (pB2 + pB3);
      u32x2 wB = {pack2bf(pB0, pB1), pack2bf(pB2, pB3)};
      *(u32x2*)&pwB[tq * PW32 + t * 8 + quad * 2] = wB;
    }
    // read P as B-fragments: lane holds P[q=tq, k=G*32+quad*8 ..+8]
    bf16x8 paA0 = *(const bf16x8*)&pwA[tq * PW32 + quad * 4];
    bf16x8 paA1 = *(const bf16x8*)&pwA[tq * PW32 + 16 + quad * 4];
    bf16x8 paB0 = *(const bf16x8*)&pwB[tq * PW32 + quad * 4];
    bf16x8 paB1 = *(const bf16x8*)&pwB[tq * PW32 + 16 + quad * 4];
    // PV swapped: A = V^T rows (d), B = P rows (q) -> O^T[row=d, col=q]
#pragma unroll
    for (int dt = 0; dt < 6; dt++) {
      const short* vp = vb + (size_t)(dt * 16 + tq) * SEQ + col0 + quad * 8;
      bf16x8 v0 = *(const bf16x8*)(vp);
      bf16x8 v1 = *(const bf16x8*)(vp + 32);
      oA[dt] = __builtin_amdgcn_mfma_f32_16x16x32_bf16(v0, paA0, oA[dt], 0, 0, 0);
      oA[dt] = __builtin_amdgcn_mfma_f32_16x16x32_bf16(v1, paA1, oA[dt], 0, 0, 0);
      oB[dt] = __builtin_amdgcn_mfma_f32_16x16x32_bf16(v0, paB0, oB[dt], 0, 0, 0);
      oB[dt] = __builtin_amdgcn_mfma_f32_16x16x32_bf16(v1, paB1, oB[dt], 0, 0, 0);
    }
  }

  // ---- (3) finalize: cross-quad l reduce, normalize, packed stores ----
  lA += __shfl_xor(lA, 16, 64);
  lA += __shfl_xor(lA, 32, 64);
  lB += __shfl_xor(lB, 16, 64);
  lB += __shfl_xor(lB, 32, 64);
  float rA = 1.f / lA, rB = 1.f / lB;
  short* hpout =
      (short*)heads + ((size_t)(b0 + bl) * SEQ) * (NHEAD * HDIM) + hh * HDIM;
  const int tokA = q0 + tq;
  const int tokB = q0 + 16 + tq;
#pragma unroll
  for (int dt = 0; dt < 6; dt++) {
    int d0 = dt * 16 + quad * 4;
    if (tokA < SEQ) {
      bf16x4 pk;
#pragma unroll
      for (int r = 0; r < 4; r++) pk[r] = f2bf(oA[dt][r] * rA);
      *(bf16x4*)(hpout + (size_t)tokA * (NHEAD * HDIM) + d0) = pk;
    }
    if (tokB < SEQ) {
      bf16x4 pk;
#pragma unroll
      for (int r = 0; r < 4; r++) pk[r] = f2bf(oB[dt][r] * rB);
      *(bf16x4*)(hpout + (size_t)tokB * (NHEAD * HDIM) + d0) = pk;
    }
  }
}

// ---------------- Kernel 4: Wo GEMM + residual + LayerNorm (MFMA, proven) --
__global__ __launch_bounds__(256) void wo_ln_mfma_kernel(
    const __hip_bfloat16* __restrict__ heads,
    const __hip_bfloat16* __restrict__ woT, const float* __restrict__ bo,
    const float* __restrict__ gamma, const float* __restrict__ beta,
    const float* __restrict__ hres, float* __restrict__ hA,
    __hip_bfloat16* __restrict__ hbf) {
  const int wave = threadIdx.x >> 6;
  const int lane = threadIdx.x & 63;
  const int tq = lane & 15;
  const int quad = lane >> 4;
  const int m0 = blockIdx.x * 64 + wave * 16;

  const short* ap = (const short*)heads + (size_t)(m0 + tq) * (NHEAD * HDIM);
  const short* bp = (const short*)woT;

  f32x4 acc[6];
  const f32x4 zero4 = {0.f, 0.f, 0.f, 0.f};
#pragma unroll
  for (int dt = 0; dt < 6; dt++) acc[dt] = zero4;

  for (int kt = 0; kt < 36; kt++) {
    bf16x8 af = *(const bf16x8*)(ap + kt * 32 + quad * 8);
#pragma unroll
    for (int dt = 0; dt < 6; dt++) {
      bf16x8 bfr = *(const bf16x8*)(bp + (size_t)(dt * 16 + tq) * (NHEAD * HDIM) +
                                    kt * 32 + quad * 8);
      acc[dt] = __builtin_amdgcn_mfma_f32_16x16x32_bf16(af, bfr, acc[dt], 0, 0, 0);
    }
  }

  const int tok0 = m0 + quad * 4;
  float s1[4] = {0.f, 0.f, 0.f, 0.f};
  float s2[4] = {0.f, 0.f, 0.f, 0.f};
#pragma unroll
  for (int dt = 0; dt < 6; dt++) {
    int n = dt * 16 + tq;
    float bias = bo[n];
#pragma unroll
    for (int r = 0; r < 4; r++) {
      float val = acc[dt][r] + bias + hres[(size_t)(tok0 + r) * EMB + n];
      acc[dt][r] = val;
      s1[r] += val;
      s2[r] += val * val;
    }
  }
#pragma unroll
  for (int mask = 1; mask < 16; mask <<= 1) {
#pragma unroll
    for (int r = 0; r < 4; r++) {
      s1[r] += __shfl_xor(s1[r], mask, 64);
      s2[r] += __shfl_xor(s2[r], mask, 64);
    }
  }
  float mean[4], rstd[4];
#pragma unroll
  for (int r = 0; r < 4; r++) {
    mean[r] = s1[r] * (1.0f / EMB);
    float var = s2[r] * (1.0f / EMB) - mean[r] * mean[r];
    rstd[r] = rsqrtf(var + EPSV);
  }
#pragma unroll
  for (int dt = 0; dt < 6; dt++) {
    int n = dt * 16 + tq;
    float g = gamma[n], bt = beta[n];
#pragma unroll
    for (int r = 0; r < 4; r++) {
      float o = (acc[dt][r] - mean[r]) * rstd[r] * g + bt;
      hA[(size_t)(tok0 + r) * EMB + n] = o;
      hbf[(size_t)(tok0 + r) * EMB + n] = __float2bfloat16(o);
    }
  }
}

// ---------------- Kernel 5: FF1 GEMM + ReLU (MFMA, proven) -----------------
__global__ __launch_bounds__(256) void ff1_mfma_kernel(
    const __hip_bfloat16* __restrict__ hbf,
    const __hip_bfloat16* __restrict__ ff1WT, const float* __restrict__ b1,
    __hip_bfloat16* __restrict__ ffbf) {
  const int wave = threadIdx.x >> 6;
  const int lane = threadIdx.x & 63;
  const int tq = lane & 15;
  const int quad = lane >> 4;
  const int m0 = blockIdx.x * 64 + wave * 16;

  const short* ap = (const short*)hbf + (size_t)(m0 + tq) * EMB + quad * 8;
  bf16x8 a0 = *(const bf16x8*)(ap);
  bf16x8 a1 = *(const bf16x8*)(ap + 32);
  bf16x8 a2 = *(const bf16x8*)(ap + 64);

  f32x4 acc[16];
  const f32x4 zero4 = {0.f, 0.f, 0.f, 0.f};
#pragma unroll
  for (int nt = 0; nt < 16; nt++) acc[nt] = zero4;
#pragma unroll
  for (int nt = 0; nt < 16; nt++) {
    const short* bp =
        (const short*)ff1WT + (size_t)(nt * 16 + tq) * EMB + quad * 8;
    bf16x8 b0f = *(const bf16x8*)(bp);
    bf16x8 b1f = *(const bf16x8*)(bp + 32);
    bf16x8 b2f = *(const bf16x8*)(bp + 64);
    acc[nt] = __builtin_amdgcn_mfma_f32_16x16x32_bf16(a0, b0f, acc[nt], 0, 0, 0);
    acc[nt] = __builtin_amdgcn_mfma_f32_16x16x32_bf16(a1, b1f, acc[nt], 0, 0, 0);
    acc[nt] = __builtin_amdgcn_mfma_f32_16x16x32_bf16(a2, b2f, acc[nt], 0, 0, 0);
  }

  const int tok0 = m0 + quad * 4;
#pragma unroll
  for (int nt = 0; nt < 16; nt++) {
    int n = nt * 16 + tq;
    float bias = b1[n];
#pragma unroll
    for (int r = 0; r < 4; r++) {
      ffbf[(size_t)(tok0 + r) * FFDIM + n] =
          __float2bfloat16(fmaxf(acc[nt][r] + bias, 0.f));
    }
  }
}

// ---------------- Kernel 6: FF2 GEMM + residual + LN (MFMA, proven) --------
__global__ __launch_bounds__(256) void ff2_ln_mfma_kernel(
    const __hip_bfloat16* __restrict__ ffbf,
    const __hip_bfloat16* __restrict__ ff2WT, const float* __restrict__ b2,
    const float* __restrict__ gamma, const float* __restrict__ beta,
    const float* __restrict__ hres, float* __restrict__ hout,
    __hip_bfloat16* __restrict__ hbf_out) {
  const int wave = threadIdx.x >> 6;
  const int lane = threadIdx.x & 63;
  const int tq = lane & 15;
  const int quad = lane >> 4;
  const int m0 = blockIdx.x * 64 + wave * 16;

  const short* ap = (const short*)ffbf + (size_t)(m0 + tq) * FFDIM;
  const short* bp = (const short*)ff2WT;

  f32x4 acc[6];
  const f32x4 zero4 = {0.f, 0.f, 0.f, 0.f};
#pragma unroll
  for (int dt = 0; dt < 6; dt++) acc[dt] = zero4;

#pragma unroll
  for (int kt = 0; kt < 8; kt++) {
    bf16x8 af = *(const bf16x8*)(ap + kt * 32 + quad * 8);
#pragma unroll
    for (int dt = 0; dt < 6; dt++) {
      bf16x8 bfr = *(const bf16x8*)(bp + (size_t)(dt * 16 + tq) * FFDIM +
                                    kt * 32 + quad * 8);
      acc[dt] = __builtin_amdgcn_mfma_f32_16x16x32_bf16(af, bfr, acc[dt], 0, 0, 0);
    }
  }

  const int tok0 = m0 + quad * 4;
  float s1[4] = {0.f, 0.f, 0.f, 0.f};
  float s2[4] = {0.f, 0.f, 0.f, 0.f};
#pragma unroll
  for (int dt = 0; dt < 6; dt++) {
    int n = dt * 16 + tq;
    float bias = b2[n];
#pragma unroll
    for (int r = 0; r < 4; r++) {
      float val = acc[dt][r] + bias + hres[(size_t)(tok0 + r) * EMB + n];
      acc[dt][r] = val;
      s1[r] += val;
      s2[r] += val * val;
    }
  }
#pragma unroll
  for (int mask = 1; mask < 16; mask <<= 1) {
#pragma unroll
    for (int r = 0; r < 4; r++) {
      s1[r] += __shfl_xor(s1[r], mask, 64);
      s2[r] += __shfl_xor(s2[r], mask, 64);
    }
  }
  float mean[4], rstd[4];
#pragma unroll
  for (int r = 0; r < 4; r++) {
    mean[r] = s1[r] * (1.0f / EMB);
    float var = s2[r] * (1.0f / EMB) - mean[r] * mean[r];
    rstd[r] = rsqrtf(var + EPSV);
  }
#pragma unroll
  for (int dt = 0; dt < 6; dt++) {
    int n = dt * 16 + tq;
    float g = gamma[n], bt = beta[n];
#pragma unroll
    for (int r = 0; r < 4; r++) {
      float o = (acc[dt][r] - mean[r]) * rstd[r] * g + bt;
      hout[(size_t)(tok0 + r) * EMB + n] = o;
      hbf_out[(size_t)(tok0 + r) * EMB + n] = __float2bfloat16(o);
    }
  }
}

// ---------------- launch ----------------------------------------------------
extern "C" void kernel_launch(void* const* d_in, const int* in_sizes, int n_in,
                              void* d_out, int out_size, void* d_ws,
                              size_t ws_size, hipStream_t stream) {
  const float* x = (const float*)d_in[0];
  const float* patch_W = (const float*)d_in[1];
  const float* patch_b = (const float*)d_in[2];
  const float* Wq = (const float*)d_in[3];
  const float* bq = (const float*)d_in[4];
  const float* Wk = (const float*)d_in[5];
  const float* bk = (const float*)d_in[6];
  const float* Wv = (const float*)d_in[7];
  const float* bv = (const float*)d_in[8];
  const float* Wo = (const float*)d_in[9];
  const float* bo = (const float*)d_in[10];
  const float* ff1_W = (const float*)d_in[11];
  const float* ff1_b = (const float*)d_in[12];
  const float* ff2_W = (const float*)d_in[13];
  const float* ff2_b = (const float*)d_in[14];
  const float* n1_g = (const float*)d_in[15];
  const float* n1_b = (const float*)d_in[16];
  const float* n2_g = (const float*)d_in[17];
  const float* n2_b = (const float*)d_in[18];

  // fixed-size pieces
  const size_t h_bytes = (size_t)TOK * EMB * sizeof(float);          // 13.76 MB
  const size_t hbf_bytes = (size_t)TOK * EMB * 2;                    // 6.88 MB
  const size_t heads_bytes = (size_t)TOK * NHEAD * HDIM * 2;         // 82.58 MB
  const size_t wqT_bytes = (size_t)NLAYER * NHEAD * HDIM * EMB * 2;  // 0.44 MB
  const size_t wkvT_bytes = 2 * wqT_bytes;                           // 0.88 MB
  const size_t woT_bytes = (size_t)NLAYER * EMB * NHEAD * HDIM * 2;  // 0.44 MB
  const size_t ffw_bytes = (size_t)NLAYER * FFDIM * EMB * 2;         // 0.10 MB
  const size_t fixed = 2 * h_bytes + hbf_bytes + heads_bytes + wqT_bytes +
                       wkvT_bytes + woT_bytes + 2 * ffw_bytes;

  // Chunk merge (round 8): 1920-block attn launches run 2.5 occupancy
  // rounds (768 resident) -> ~17% tail idle. chunk=64 -> 3840 blocks =
  // exactly 5.0 rounds, no tail, and halves kv/attn launch count. Needs
  // ~284 MB workspace (kv bufs double); fall back to chunk=32 otherwise.
  const size_t kvb64 = (size_t)64 * NHEAD * SEQ * HDIM * 2;  // 82.58 MB
  const size_t kvb32 = (size_t)32 * NHEAD * SEQ * HDIM * 2;  // 41.29 MB
  int chunk = (ws_size >= fixed + 2 * kvb64) ? 64 : 32;
  const size_t kv_bytes = (chunk == 64) ? kvb64 : kvb32;

  char* ws = (char*)d_ws;
  size_t off = 0;
  float* h = (float*)(ws + off); off += h_bytes;
  float* hA = (float*)(ws + off); off += h_bytes;
  __hip_bfloat16* hbf = (__hip_bfloat16*)(ws + off); off += hbf_bytes;
  __hip_bfloat16* kbuf = (__hip_bfloat16*)(ws + off); off += kv_bytes;
  __hip_bfloat16* vbufT = (__hip_bfloat16*)(ws + off); off += kv_bytes;
  __hip_bfloat16* heads = (__hip_bfloat16*)(ws + off); off += heads_bytes;
  __hip_bfloat16* wqT = (__hip_bfloat16*)(ws + off); off += wqT_bytes;
  __hip_bfloat16* wkvT = (__hip_bfloat16*)(ws + off); off += wkvT_bytes;
  __hip_bfloat16* woT = (__hip_bfloat16*)(ws + off); off += woT_bytes;
  __hip_bfloat16* ff1WT = (__hip_bfloat16*)(ws + off); off += ffw_bytes;
  __hip_bfloat16* ff2WT = (__hip_bfloat16*)(ws + off); off += ffw_bytes;
  __hip_bfloat16* ffbf = (__hip_bfloat16*)kbuf;  // alias: free after attention

  allprep_kernel<<<78, 256, 0, stream>>>(Wq, Wk, Wv, Wo, ff1_W, ff2_W, wqT,
                                         wkvT, woT, ff1WT, ff2WT);
  patch_pe_kernel<<<(TOK * EMB + 255) / 256, 256, 0, stream>>>(x, patch_W,
                                                               patch_b, h, hbf);

  for (int l = 0; l < NLAYER; l++) {
    const __hip_bfloat16* wqT_l = wqT + (size_t)l * NHEAD * HDIM * EMB;
    const __hip_bfloat16* wkvT_l = wkvT + (size_t)l * 2 * NHEAD * HDIM * EMB;
    const __hip_bfloat16* woT_l = woT + (size_t)l * EMB * NHEAD * HDIM;
    const __hip_bfloat16* ff1WT_l = ff1WT + (size_t)l * FFDIM * EMB;
    const __hip_bfloat16* ff2WT_l = ff2WT + (size_t)l * EMB * FFDIM;
    const float* bq_l = bq + (size_t)l * NHEAD * HDIM;
    const float* bk_l = bk + (size_t)l * NHEAD * HDIM;
    const float* bv_l = bv + (size_t)l * NHEAD * HDIM;
    const float* bo_l = bo + (size_t)l * EMB;

    for (int c = 0; c < BATCH / chunk; c++) {
      int b0 = c * chunk;
      kv_mfma_kernel<<<dim3(chunk * SEQ / 64, 2 * NHEAD * HDIM / 64), 256, 0,
                       stream>>>(hbf, wkvT_l, bk_l, bv_l, kbuf, vbufT, b0);
      // 5 q-blocks (128 rows each) x (chunk*12) groups, XCD-swizzled
      attn_flash_kernel<<<5 * NHEAD * chunk, 256, 0, stream>>>(
          hbf, wqT_l, bq_l, kbuf, vbufT, heads, b0);
    }
    // LN1: reads residual h, writes hA (fp32) + hbf (bf16)
    wo_ln_mfma_kernel<<<TOK / 64, 256, 0, stream>>>(
        heads, woT_l, bo_l, n1_g + l * EMB, n1_b + l * EMB, h, hA, hbf);
    // FF path (MFMA, split, proven): ff1 reads hbf -> ffbf; ff2 reads ffbf + hA
    ff1_mfma_kernel<<<TOK / 64, 256, 0, stream>>>(hbf, ff1WT_l,
                                                  ff1_b + l * FFDIM, ffbf);
    float* dst = (l == NLAYER - 1) ? (float*)d_out : h;
    ff2_ln_mfma_kernel<<<TOK / 64, 256, 0, stream>>>(
        ffbf, ff2WT_l, ff2_b + l * EMB, n2_g + l * EMB, n2_b + l * EMB, hA,
        dst, hbf);
  }
}

// Round 9
// 1189.245 us; speedup vs baseline: 1.2298x; 1.0022x over previous
//
#include <hip/hip_runtime.h>
#include <hip/hip_bf16.h>
#include <math.h>

#define BATCH 64
#define INPUT_SIZE 10080
#define PATCH 18
#define SEQ 560            // S
#define EMB 96             // E
#define NHEAD 12           // H
#define HDIM 96            // D
#define FFDIM 256          // F
#define NLAYER 2
#define TOK (BATCH * SEQ)  // 35840 tokens
#define EPSV 1e-5f
#define SCALE 0.10206207261596577f      // 1/sqrt(96)
#define SCALE_L2E 0.14724443805513492f  // SCALE * log2(e): scores in log2 space

typedef __attribute__((ext_vector_type(8))) short bf16x8;  // 8 bf16 (4 VGPRs)
typedef __attribute__((ext_vector_type(4))) short bf16x4;  // 4 bf16 (8B store)
typedef __attribute__((ext_vector_type(4))) float f32x4;   // 4 fp32 acc
typedef __attribute__((ext_vector_type(2))) unsigned int u32x2;

static __device__ __forceinline__ short f2bf(float x) {
  union { __hip_bfloat16 b; short s; } u;
  u.b = __float2bfloat16(x);
  return u.s;
}

// pack two floats as 2 bf16 in one u32 (lo in low half)
static __device__ __forceinline__ unsigned int pack2bf(float lo, float hi) {
  unsigned int a = (unsigned short)f2bf(lo);
  unsigned int b = (unsigned short)f2bf(hi);
  return a | (b << 16);
}

// raw v_exp_f32: 2^x (scores are pre-scaled by log2(e))
static __device__ __forceinline__ float exp2_fast(float x) {
  float r;
  asm("v_exp_f32 %0, %1" : "=v"(r) : "v"(x));
  return r;
}

// ---------------- Kernel 0: all weight transposes, one launch --------------
__global__ __launch_bounds__(256) void allprep_kernel(
    const float* __restrict__ Wq, const float* __restrict__ Wk,
    const float* __restrict__ Wv, const float* __restrict__ Wo,
    const float* __restrict__ ff1_W, const float* __restrict__ ff2_W,
    __hip_bfloat16* __restrict__ wqT, __hip_bfloat16* __restrict__ wkvT,
    __hip_bfloat16* __restrict__ woT, __hip_bfloat16* __restrict__ ff1WT,
    __hip_bfloat16* __restrict__ ff2WT) {
  int bx = blockIdx.x;
  if (bx < 72) {
    int hh = bx % NHEAD, mat = (bx / NHEAD) % 3, l = bx / 36;
    const float* src = (mat == 0 ? Wq : (mat == 1 ? Wk : Wv)) +
                       ((size_t)l * NHEAD + hh) * EMB * HDIM;
    __shared__ float t[HDIM * 97];
    for (int i = threadIdx.x; i < EMB * HDIM; i += 256) {
      int e = i / HDIM, d = i % HDIM;
      t[d * 97 + e] = src[i];
    }
    __syncthreads();
    __hip_bfloat16* dst;
    if (mat == 0)
      dst = wqT + ((size_t)l * NHEAD + hh) * HDIM * EMB;
    else
      dst = wkvT + ((size_t)l * 2 * NHEAD * HDIM + (mat - 1) * NHEAD * HDIM +
                    hh * HDIM) * EMB;
    for (int j = threadIdx.x; j < HDIM * EMB; j += 256) {
      int d = j / EMB, e = j % EMB;
      dst[j] = __float2bfloat16(t[d * 97 + e]);
    }
  } else if (bx < 74) {
    int l = bx - 72;
    const float* src = Wo + (size_t)l * NHEAD * HDIM * EMB;
    __hip_bfloat16* dst = woT + (size_t)l * EMB * NHEAD * HDIM;
    for (int i = threadIdx.x; i < EMB * NHEAD * HDIM; i += 256) {
      int e = i / (NHEAD * HDIM), j = i % (NHEAD * HDIM);
      dst[i] = __float2bfloat16(src[(size_t)j * EMB + e]);
    }
  } else {
    int idx = bx - 74;
    int mat = idx % 2, l = idx / 2;
    if (mat == 0) {
      const float* src = ff1_W + (size_t)l * EMB * FFDIM;
      __hip_bfloat16* dst = ff1WT + (size_t)l * FFDIM * EMB;
      for (int i = threadIdx.x; i < FFDIM * EMB; i += 256) {
        int f = i / EMB, e = i % EMB;
        dst[i] = __float2bfloat16(src[(size_t)e * FFDIM + f]);
      }
    } else {
      const float* src = ff2_W + (size_t)l * FFDIM * EMB;
      __hip_bfloat16* dst = ff2WT + (size_t)l * EMB * FFDIM;
      for (int i = threadIdx.x; i < EMB * FFDIM; i += 256) {
        int e = i / FFDIM, f = i % FFDIM;
        dst[i] = __float2bfloat16(src[(size_t)f * EMB + e]);
      }
    }
  }
}

// ---------------- Kernel 1: patch embedding + sinusoidal PE ----------------
__global__ void patch_pe_kernel(const float* __restrict__ x,
                                const float* __restrict__ W,
                                const float* __restrict__ bias,
                                float* __restrict__ h,
                                __hip_bfloat16* __restrict__ hbf) {
  int gid = blockIdx.x * blockDim.x + threadIdx.x;
  if (gid >= TOK * EMB) return;
  int tok = gid / EMB;
  int e = gid % EMB;
  int b = tok / SEQ;
  int s = tok % SEQ;
  const float* xp = x + b * INPUT_SIZE + s * PATCH;
  float acc = bias[e];
#pragma unroll
  for (int p = 0; p < PATCH; p++) acc += xp[p] * W[p * EMB + e];
  int i = e >> 1;
  float freq = __expf(-(float)(2 * i) * (9.210340371976184f / 96.0f));
  float ang = (float)s * freq;
  acc += (e & 1) ? cosf(ang) : sinf(ang);
  h[gid] = acc;
  hbf[gid] = __float2bfloat16(acc);
}

// ---------------- Kernel 2: K/V projection GEMM (MFMA) ---------------------
// Works for any batch-chunk size: m0 spans [0, chunk*SEQ) via gridDim.x.
__global__ __launch_bounds__(256) void kv_mfma_kernel(
    const __hip_bfloat16* __restrict__ hbf,
    const __hip_bfloat16* __restrict__ wkvT, const float* __restrict__ bk,
    const float* __restrict__ bv, __hip_bfloat16* __restrict__ kbuf,
    __hip_bfloat16* __restrict__ vbufT, int b0) {
  const int wave = threadIdx.x >> 6;
  const int lane = threadIdx.x & 63;
  const int tq = lane & 15;
  const int quad = lane >> 4;
  const int m0 = blockIdx.x * 64 + wave * 16;  // token tile row (chunk-local)
  const int n0 = blockIdx.y * 64;

  __shared__ short tile[4][16][68];  // wave-local K bounce (8.7 KB)

  const short* ap =
      (const short*)hbf + ((size_t)b0 * SEQ + m0 + tq) * EMB + quad * 8;
  bf16x8 a0 = *(const bf16x8*)(ap);
  bf16x8 a1 = *(const bf16x8*)(ap + 32);
  bf16x8 a2 = *(const bf16x8*)(ap + 64);

  f32x4 acc[4];
  const f32x4 zero4 = {0.f, 0.f, 0.f, 0.f};
#pragma unroll
  for (int nt = 0; nt < 4; nt++) acc[nt] = zero4;
#pragma unroll
  for (int nt = 0; nt < 4; nt++) {
    const short* bp =
        (const short*)wkvT + (size_t)(n0 + nt * 16 + tq) * EMB + quad * 8;
    bf16x8 b0f = *(const bf16x8*)(bp);
    bf16x8 b1f = *(const bf16x8*)(bp + 32);
    bf16x8 b2f = *(const bf16x8*)(bp + 64);
    acc[nt] = __builtin_amdgcn_mfma_f32_16x16x32_bf16(a0, b0f, acc[nt], 0, 0, 0);
    acc[nt] = __builtin_amdgcn_mfma_f32_16x16x32_bf16(a1, b1f, acc[nt], 0, 0, 0);
    acc[nt] = __builtin_amdgcn_mfma_f32_16x16x32_bf16(a2, b2f, acc[nt], 0, 0, 0);
  }

  const int tl0 = m0 + quad * 4;
  const int blb = tl0 / SEQ;
  const int ss0 = tl0 - blb * SEQ;

  if (n0 < NHEAD * HDIM) {
#pragma unroll
    for (int nt = 0; nt < 4; nt++) {
      int n = n0 + nt * 16 + tq;
      float bias = bk[n];
#pragma unroll
      for (int j = 0; j < 4; j++)
        tile[wave][quad * 4 + j][nt * 16 + tq] = f2bf(acc[nt][j] + bias);
    }
#pragma unroll
    for (int it = 0; it < 2; it++) {
      int idx = it * 64 + lane;
      int row = idx >> 3;
      int seg = idx & 7;
      int tl = m0 + row;
      int bb = tl / SEQ;
      int ss = tl - bb * SEQ;
      int r0s = n0 + seg * 8;
      int hh2 = r0s / HDIM;
      int d0 = r0s - hh2 * HDIM;
      bf16x8 v = *(const bf16x8*)&tile[wave][row][seg * 8];
      *(bf16x8*)((short*)kbuf +
                 ((size_t)(bb * NHEAD + hh2) * SEQ + ss) * HDIM + d0) = v;
    }
  } else {
#pragma unroll
    for (int nt = 0; nt < 4; nt++) {
      int n = n0 + nt * 16 + tq;
      int r = n - NHEAD * HDIM;
      int hh2 = r / HDIM;
      int d = r - hh2 * HDIM;
      float bias = bv[r];
      bf16x4 pack;
#pragma unroll
      for (int j = 0; j < 4; j++) pack[j] = f2bf(acc[nt][j] + bias);
      *(bf16x4*)((short*)vbufT +
                 ((size_t)(blb * NHEAD + hh2) * HDIM + d) * SEQ + ss0) = pack;
    }
  }
}

// ---------------- Kernel 3: flash attention, transposed softmax ------------
// (round-3 proven structure, byte-identical: 158 us/1920-block launch)
// Swapped MFMA operands: S^T = mfma(K,Q), O^T = mfma(V^T,P).
// Lane holds one q-row (q = lane&15): m/l are scalars, chunk-max is in-lane
// + 2 shuffles, rescale factors lane-local. P bounce: 8B packed writes.
// __launch_bounds__(256,3): keeps co-resident groups/XCD * 215KB panel under
// the 4MB L2 (bounds(256,4) thrashed L2: FETCH 58->195MB, dur +28%).
// FAILED variants (do not retry): K reg-double-buffer (r4: +48 VGPR > 170
// combined budget -> scratch spill, WRITE 40->380MB); setprio around MFMA
// (r5: -4%, QK cluster contains K loads); 512-thr 16-row waves (r7: 2x VMEM
// issue per row, occupancy stuck 32% -> 158->233us). Combined reg usage is
// ~155/170 at 3 waves/EU: NO headroom for any +24/+48-reg prefetch.
#define QW 104   // Q bounce row stride (shorts): 208B rows, 16B-aligned
#define PW32 36  // P bounce row stride (u32): 144B rows, 16B-aligned
__global__ __launch_bounds__(256, 3) void attn_flash_kernel(
    const __hip_bfloat16* __restrict__ hbf,
    const __hip_bfloat16* __restrict__ wqT, const float* __restrict__ bq,
    const __hip_bfloat16* __restrict__ kbuf,
    const __hip_bfloat16* __restrict__ vbufT,
    __hip_bfloat16* __restrict__ heads, int b0) {
  const int flat = blockIdx.x;
  const int xcd = flat & 7;
  const int slot = flat >> 3;
  const int g = (slot / 5) * 8 + xcd;  // group = (bl,hh), XCD-local
  const int qt = slot % 5;             // 0..4, 128 q-rows per block
  const int hh = g % NHEAD;
  const int bl = g / NHEAD;            // chunk-local batch
  const int wave = threadIdx.x >> 6;
  const int lane = threadIdx.x & 63;
  const int tq = lane & 15;
  const int quad = lane >> 4;

  __shared__ __align__(16) short sbuf[4][3328];  // 26,624 B total
  short* pw = sbuf[wave];                        // wave-private region
  unsigned int* pwA = (unsigned int*)pw;         // P set A: 16 x PW32 u32
  unsigned int* pwB = pwA + 16 * PW32;           // P set B: 16 x PW32 u32

  const size_t bh = (size_t)(bl * NHEAD + hh);
  const short* kb = (const short*)kbuf + bh * SEQ * HDIM;
  const short* vb = (const short*)vbufT + bh * HDIM * SEQ;

  const int q0 = qt * 128 + wave * 32;

  // ---- (1) Q projection via MFMA for two 16-row tiles ----
  int qrA = q0 + tq;      if (qrA > SEQ - 1) qrA = SEQ - 1;
  int qrB = q0 + 16 + tq; if (qrB > SEQ - 1) qrB = SEQ - 1;
  const short* hpA =
      (const short*)hbf + ((size_t)(b0 + bl) * SEQ + qrA) * EMB + quad * 8;
  const short* hpB =
      (const short*)hbf + ((size_t)(b0 + bl) * SEQ + qrB) * EMB + quad * 8;
  bf16x8 haA0 = *(const bf16x8*)(hpA);
  bf16x8 haA1 = *(const bf16x8*)(hpA + 32);
  bf16x8 haA2 = *(const bf16x8*)(hpA + 64);
  bf16x8 haB0 = *(const bf16x8*)(hpB);
  bf16x8 haB1 = *(const bf16x8*)(hpB + 32);
  bf16x8 haB2 = *(const bf16x8*)(hpB + 64);
  const f32x4 zero4 = {0.f, 0.f, 0.f, 0.f};
  f32x4 qaccA[6], qaccB[6];
#pragma unroll
  for (int dt = 0; dt < 6; dt++) { qaccA[dt] = zero4; qaccB[dt] = zero4; }
#pragma unroll
  for (int dt = 0; dt < 6; dt++) {
    const short* wp = (const short*)wqT +
                      ((size_t)hh * HDIM + dt * 16 + tq) * EMB + quad * 8;
    bf16x8 w0 = *(const bf16x8*)(wp);
    bf16x8 w1 = *(const bf16x8*)(wp + 32);
    bf16x8 w2 = *(const bf16x8*)(wp + 64);
    qaccA[dt] = __builtin_amdgcn_mfma_f32_16x16x32_bf16(haA0, w0, qaccA[dt], 0, 0, 0);
    qaccA[dt] = __builtin_amdgcn_mfma_f32_16x16x32_bf16(haA1, w1, qaccA[dt], 0, 0, 0);
    qaccA[dt] = __builtin_amdgcn_mfma_f32_16x16x32_bf16(haA2, w2, qaccA[dt], 0, 0, 0);
    qaccB[dt] = __builtin_amdgcn_mfma_f32_16x16x32_bf16(haB0, w0, qaccB[dt], 0, 0, 0);
    qaccB[dt] = __builtin_amdgcn_mfma_f32_16x16x32_bf16(haB1, w1, qaccB[dt], 0, 0, 0);
    qaccB[dt] = __builtin_amdgcn_mfma_f32_16x16x32_bf16(haB2, w2, qaccB[dt], 0, 0, 0);
  }
#pragma unroll
  for (int dt = 0; dt < 6; dt++) {
    int d = dt * 16 + tq;
    float bias = bq[hh * HDIM + d];
#pragma unroll
    for (int r = 0; r < 4; r++) {
      pw[(quad * 4 + r) * QW + d] = f2bf((qaccA[dt][r] + bias) * SCALE_L2E);
      pw[(16 + quad * 4 + r) * QW + d] = f2bf((qaccB[dt][r] + bias) * SCALE_L2E);
    }
  }
  bf16x8 aqA0 = *(const bf16x8*)&pw[tq * QW + quad * 8];
  bf16x8 aqA1 = *(const bf16x8*)&pw[tq * QW + 32 + quad * 8];
  bf16x8 aqA2 = *(const bf16x8*)&pw[tq * QW + 64 + quad * 8];
  bf16x8 aqB0 = *(const bf16x8*)&pw[(16 + tq) * QW + quad * 8];
  bf16x8 aqB1 = *(const bf16x8*)&pw[(16 + tq) * QW + 32 + quad * 8];
  bf16x8 aqB2 = *(const bf16x8*)&pw[(16 + tq) * QW + 64 + quad * 8];
  // Q region dead once aq regs are loaded; pwA/pwB reuse it (same wave).

  // ---- (2) online-softmax main loop, transposed space -------------------
  // S^T tile layout: col = q = tq (lane-local), row = k = 16t + quad*4 + r.
  f32x4 oA[6], oB[6];  // O^T: col = q = tq, row = d = 16dt + quad*4 + r
#pragma unroll
  for (int dt = 0; dt < 6; dt++) { oA[dt] = zero4; oB[dt] = zero4; }
  float mA = -1e30f, mB = -1e30f, lA = 0.f, lB = 0.f;

  for (int c = 0; c < 9; c++) {
    const int col0 = c * 64;
    f32x4 sA[4], sB[4];
#pragma unroll
    for (int t = 0; t < 4; t++) { sA[t] = zero4; sB[t] = zero4; }
#pragma unroll
    for (int t = 0; t < 4; t++) {
      const short* kp = kb + (size_t)(col0 + t * 16 + tq) * HDIM + quad * 8;
      bf16x8 k0 = *(const bf16x8*)(kp);
      bf16x8 k1 = *(const bf16x8*)(kp + 32);
      bf16x8 k2 = *(const bf16x8*)(kp + 64);
      // swapped: A = K rows, B = Q rows -> C[row=k, col=q]
      sA[t] = __builtin_amdgcn_mfma_f32_16x16x32_bf16(k0, aqA0, sA[t], 0, 0, 0);
      sA[t] = __builtin_amdgcn_mfma_f32_16x16x32_bf16(k1, aqA1, sA[t], 0, 0, 0);
      sA[t] = __builtin_amdgcn_mfma_f32_16x16x32_bf16(k2, aqA2, sA[t], 0, 0, 0);
      sB[t] = __builtin_amdgcn_mfma_f32_16x16x32_bf16(k0, aqB0, sB[t], 0, 0, 0);
      sB[t] = __builtin_amdgcn_mfma_f32_16x16x32_bf16(k1, aqB1, sB[t], 0, 0, 0);
      sB[t] = __builtin_amdgcn_mfma_f32_16x16x32_bf16(k2, aqB2, sB[t], 0, 0, 0);
    }
    if (c == 8) {  // k rows 560..575 out of range (tile t=3): mask
#pragma unroll
      for (int r = 0; r < 4; r++) { sA[3][r] = -1e30f; sB[3][r] = -1e30f; }
    }
    // chunk max: in-lane over 16 k's, then across quads (2 shuffles)
    float cA = sA[0][0], cB = sB[0][0];
#pragma unroll
    for (int t = 0; t < 4; t++) {
#pragma unroll
      for (int r = 0; r < 4; r++) {
        cA = fmaxf(cA, sA[t][r]);
        cB = fmaxf(cB, sB[t][r]);
      }
    }
    cA = fmaxf(cA, __shfl_xor(cA, 16, 64));
    cA = fmaxf(cA, __shfl_xor(cA, 32, 64));
    cB = fmaxf(cB, __shfl_xor(cB, 16, 64));
    cB = fmaxf(cB, __shfl_xor(cB, 32, 64));
    // exact skip-rescale (lane-local scalars, wave-uniform branch)
    if (__any((cA > mA) | (cB > mB))) {
      float mnA = fmaxf(mA, cA);
      float fA = exp2_fast(mA - mnA);
      mA = mnA; lA *= fA;
      float mnB = fmaxf(mB, cB);
      float fB = exp2_fast(mB - mnB);
      mB = mnB; lB *= fB;
#pragma unroll
      for (int dt = 0; dt < 6; dt++) {
#pragma unroll
        for (int r = 0; r < 4; r++) { oA[dt][r] *= fA; oB[dt][r] *= fB; }
      }
    }
    // P = 2^(s-m); pack pairs; wave-private LDS bounce (row q=tq)
#pragma unroll
    for (int t = 0; t < 4; t++) {
      float pA0 = exp2_fast(sA[t][0] - mA);
      float pA1 = exp2_fast(sA[t][1] - mA);
      float pA2 = exp2_fast(sA[t][2] - mA);
      float pA3 = exp2_fast(sA[t][3] - mA);
      lA += (pA0 + pA1) + (pA2 + pA3);
      u32x2 wA = {pack2bf(pA0, pA1), pack2bf(pA2, pA3)};
      *(u32x2*)&pwA[tq * PW32 + t * 8 + quad * 2] = wA;
      float pB0 = exp2_fast(sB[t][0] - mB);
      float pB1 = exp2_fast(sB[t][1] - mB);
      float pB2 = exp2_fast(sB[t][2] - mB);
      float pB3 = exp2_fast(sB[t][3] - mB);
      lB += (pB0 + pB1) + (pB2 + pB3);
      u32x2 wB = {pack2bf(pB0, pB1), pack2bf(pB2, pB3)};
      *(u32x2*)&pwB[tq * PW32 + t * 8 + quad * 2] = wB;
    }
    // read P as B-fragments: lane holds P[q=tq, k=G*32+quad*8 ..+8]
    bf16x8 paA0 = *(const bf16x8*)&pwA[tq * PW32 + quad * 4];
    bf16x8 paA1 = *(const bf16x8*)&pwA[tq * PW32 + 16 + quad * 4];
    bf16x8 paB0 = *(const bf16x8*)&pwB[tq * PW32 + quad * 4];
    bf16x8 paB1 = *(const bf16x8*)&pwB[tq * PW32 + 16 + quad * 4];
    // PV swapped: A = V^T rows (d), B = P rows (q) -> O^T[row=d, col=q]
#pragma unroll
    for (int dt = 0; dt < 6; dt++) {
      const short* vp = vb + (size_t)(dt * 16 + tq) * SEQ + col0 + quad * 8;
      bf16x8 v0 = *(const bf16x8*)(vp);
      bf16x8 v1 = *(const bf16x8*)(vp + 32);
      oA[dt] = __builtin_amdgcn_mfma_f32_16x16x32_bf16(v0, paA0, oA[dt], 0, 0, 0);
      oA[dt] = __builtin_amdgcn_mfma_f32_16x16x32_bf16(v1, paA1, oA[dt], 0, 0, 0);
      oB[dt] = __builtin_amdgcn_mfma_f32_16x16x32_bf16(v0, paB0, oB[dt], 0, 0, 0);
      oB[dt] = __builtin_amdgcn_mfma_f32_16x16x32_bf16(v1, paB1, oB[dt], 0, 0, 0);
    }
  }

  // ---- (3) finalize: cross-quad l reduce, normalize, packed stores ----
  lA += __shfl_xor(lA, 16, 64);
  lA += __shfl_xor(lA, 32, 64);
  lB += __shfl_xor(lB, 16, 64);
  lB += __shfl_xor(lB, 32, 64);
  float rA = 1.f / lA, rB = 1.f / lB;
  short* hpout =
      (short*)heads + ((size_t)(b0 + bl) * SEQ) * (NHEAD * HDIM) + hh * HDIM;
  const int tokA = q0 + tq;
  const int tokB = q0 + 16 + tq;
#pragma unroll
  for (int dt = 0; dt < 6; dt++) {
    int d0 = dt * 16 + quad * 4;
    if (tokA < SEQ) {
      bf16x4 pk;
#pragma unroll
      for (int r = 0; r < 4; r++) pk[r] = f2bf(oA[dt][r] * rA);
      *(bf16x4*)(hpout + (size_t)tokA * (NHEAD * HDIM) + d0) = pk;
    }
    if (tokB < SEQ) {
      bf16x4 pk;
#pragma unroll
      for (int r = 0; r < 4; r++) pk[r] = f2bf(oB[dt][r] * rB);
      *(bf16x4*)(hpout + (size_t)tokB * (NHEAD * HDIM) + d0) = pk;
    }
  }
}

// ---------------- Kernel 4: Wo GEMM + residual + LayerNorm (MFMA, proven) --
__global__ __launch_bounds__(256) void wo_ln_mfma_kernel(
    const __hip_bfloat16* __restrict__ heads,
    const __hip_bfloat16* __restrict__ woT, const float* __restrict__ bo,
    const float* __restrict__ gamma, const float* __restrict__ beta,
    const float* __restrict__ hres, float* __restrict__ hA,
    __hip_bfloat16* __restrict__ hbf) {
  const int wave = threadIdx.x >> 6;
  const int lane = threadIdx.x & 63;
  const int tq = lane & 15;
  const int quad = lane >> 4;
  const int m0 = blockIdx.x * 64 + wave * 16;

  const short* ap = (const short*)heads + (size_t)(m0 + tq) * (NHEAD * HDIM);
  const short* bp = (const short*)woT;

  f32x4 acc[6];
  const f32x4 zero4 = {0.f, 0.f, 0.f, 0.f};
#pragma unroll
  for (int dt = 0; dt < 6; dt++) acc[dt] = zero4;

  for (int kt = 0; kt < 36; kt++) {
    bf16x8 af = *(const bf16x8*)(ap + kt * 32 + quad * 8);
#pragma unroll
    for (int dt = 0; dt < 6; dt++) {
      bf16x8 bfr = *(const bf16x8*)(bp + (size_t)(dt * 16 + tq) * (NHEAD * HDIM) +
                                    kt * 32 + quad * 8);
      acc[dt] = __builtin_amdgcn_mfma_f32_16x16x32_bf16(af, bfr, acc[dt], 0, 0, 0);
    }
  }

  const int tok0 = m0 + quad * 4;
  float s1[4] = {0.f, 0.f, 0.f, 0.f};
  float s2[4] = {0.f, 0.f, 0.f, 0.f};
#pragma unroll
  for (int dt = 0; dt < 6; dt++) {
    int n = dt * 16 + tq;
    float bias = bo[n];
#pragma unroll
    for (int r = 0; r < 4; r++) {
      float val = acc[dt][r] + bias + hres[(size_t)(tok0 + r) * EMB + n];
      acc[dt][r] = val;
      s1[r] += val;
      s2[r] += val * val;
    }
  }
#pragma unroll
  for (int mask = 1; mask < 16; mask <<= 1) {
#pragma unroll
    for (int r = 0; r < 4; r++) {
      s1[r] += __shfl_xor(s1[r], mask, 64);
      s2[r] += __shfl_xor(s2[r], mask, 64);
    }
  }
  float mean[4], rstd[4];
#pragma unroll
  for (int r = 0; r < 4; r++) {
    mean[r] = s1[r] * (1.0f / EMB);
    float var = s2[r] * (1.0f / EMB) - mean[r] * mean[r];
    rstd[r] = rsqrtf(var + EPSV);
  }
#pragma unroll
  for (int dt = 0; dt < 6; dt++) {
    int n = dt * 16 + tq;
    float g = gamma[n], bt = beta[n];
#pragma unroll
    for (int r = 0; r < 4; r++) {
      float o = (acc[dt][r] - mean[r]) * rstd[r] * g + bt;
      hA[(size_t)(tok0 + r) * EMB + n] = o;
      hbf[(size_t)(tok0 + r) * EMB + n] = __float2bfloat16(o);
    }
  }
}

// ---------------- Kernel 5: FF1 GEMM + ReLU (MFMA, proven) -----------------
__global__ __launch_bounds__(256) void ff1_mfma_kernel(
    const __hip_bfloat16* __restrict__ hbf,
    const __hip_bfloat16* __restrict__ ff1WT, const float* __restrict__ b1,
    __hip_bfloat16* __restrict__ ffbf) {
  const int wave = threadIdx.x >> 6;
  const int lane = threadIdx.x & 63;
  const int tq = lane & 15;
  const int quad = lane >> 4;
  const int m0 = blockIdx.x * 64 + wave * 16;

  const short* ap = (const short*)hbf + (size_t)(m0 + tq) * EMB + quad * 8;
  bf16x8 a0 = *(const bf16x8*)(ap);
  bf16x8 a1 = *(const bf16x8*)(ap + 32);
  bf16x8 a2 = *(const bf16x8*)(ap + 64);

  f32x4 acc[16];
  const f32x4 zero4 = {0.f, 0.f, 0.f, 0.f};
#pragma unroll
  for (int nt = 0; nt < 16; nt++) acc[nt] = zero4;
#pragma unroll
  for (int nt = 0; nt < 16; nt++) {
    const short* bp =
        (const short*)ff1WT + (size_t)(nt * 16 + tq) * EMB + quad * 8;
    bf16x8 b0f = *(const bf16x8*)(bp);
    bf16x8 b1f = *(const bf16x8*)(bp + 32);
    bf16x8 b2f = *(const bf16x8*)(bp + 64);
    acc[nt] = __builtin_amdgcn_mfma_f32_16x16x32_bf16(a0, b0f, acc[nt], 0, 0, 0);
    acc[nt] = __builtin_amdgcn_mfma_f32_16x16x32_bf16(a1, b1f, acc[nt], 0, 0, 0);
    acc[nt] = __builtin_amdgcn_mfma_f32_16x16x32_bf16(a2, b2f, acc[nt], 0, 0, 0);
  }

  const int tok0 = m0 + quad * 4;
#pragma unroll
  for (int nt = 0; nt < 16; nt++) {
    int n = nt * 16 + tq;
    float bias = b1[n];
#pragma unroll
    for (int r = 0; r < 4; r++) {
      ffbf[(size_t)(tok0 + r) * FFDIM + n] =
          __float2bfloat16(fmaxf(acc[nt][r] + bias, 0.f));
    }
  }
}

// ---------------- Kernel 6: FF2 GEMM + residual + LN (MFMA, proven) --------
__global__ __launch_bounds__(256) void ff2_ln_mfma_kernel(
    const __hip_bfloat16* __restrict__ ffbf,
    const __hip_bfloat16* __restrict__ ff2WT, const float* __restrict__ b2,
    const float* __restrict__ gamma, const float* __restrict__ beta,
    const float* __restrict__ hres, float* __restrict__ hout,
    __hip_bfloat16* __restrict__ hbf_out) {
  const int wave = threadIdx.x >> 6;
  const int lane = threadIdx.x & 63;
  const int tq = lane & 15;
  const int quad = lane >> 4;
  const int m0 = blockIdx.x * 64 + wave * 16;

  const short* ap = (const short*)ffbf + (size_t)(m0 + tq) * FFDIM;
  const short* bp = (const short*)ff2WT;

  f32x4 acc[6];
  const f32x4 zero4 = {0.f, 0.f, 0.f, 0.f};
#pragma unroll
  for (int dt = 0; dt < 6; dt++) acc[dt] = zero4;

#pragma unroll
  for (int kt = 0; kt < 8; kt++) {
    bf16x8 af = *(const bf16x8*)(ap + kt * 32 + quad * 8);
#pragma unroll
    for (int dt = 0; dt < 6; dt++) {
      bf16x8 bfr = *(const bf16x8*)(bp + (size_t)(dt * 16 + tq) * FFDIM +
                                    kt * 32 + quad * 8);
      acc[dt] = __builtin_amdgcn_mfma_f32_16x16x32_bf16(af, bfr, acc[dt], 0, 0, 0);
    }
  }

  const int tok0 = m0 + quad * 4;
  float s1[4] = {0.f, 0.f, 0.f, 0.f};
  float s2[4] = {0.f, 0.f, 0.f, 0.f};
#pragma unroll
  for (int dt = 0; dt < 6; dt++) {
    int n = dt * 16 + tq;
    float bias = b2[n];
#pragma unroll
    for (int r = 0; r < 4; r++) {
      float val = acc[dt][r] + bias + hres[(size_t)(tok0 + r) * EMB + n];
      acc[dt][r] = val;
      s1[r] += val;
      s2[r] += val * val;
    }
  }
#pragma unroll
  for (int mask = 1; mask < 16; mask <<= 1) {
#pragma unroll
    for (int r = 0; r < 4; r++) {
      s1[r] += __shfl_xor(s1[r], mask, 64);
      s2[r] += __shfl_xor(s2[r], mask, 64);
    }
  }
  float mean[4], rstd[4];
#pragma unroll
  for (int r = 0; r < 4; r++) {
    mean[r] = s1[r] * (1.0f / EMB);
    float var = s2[r] * (1.0f / EMB) - mean[r] * mean[r];
    rstd[r] = rsqrtf(var + EPSV);
  }
#pragma unroll
  for (int dt = 0; dt < 6; dt++) {
    int n = dt * 16 + tq;
    float g = gamma[n], bt = beta[n];
#pragma unroll
    for (int r = 0; r < 4; r++) {
      float o = (acc[dt][r] - mean[r]) * rstd[r] * g + bt;
      hout[(size_t)(tok0 + r) * EMB + n] = o;
      hbf_out[(size_t)(tok0 + r) * EMB + n] = __float2bfloat16(o);
    }
  }
}

// ---------------- launch ----------------------------------------------------
extern "C" void kernel_launch(void* const* d_in, const int* in_sizes, int n_in,
                              void* d_out, int out_size, void* d_ws,
                              size_t ws_size, hipStream_t stream) {
  const float* x = (const float*)d_in[0];
  const float* patch_W = (const float*)d_in[1];
  const float* patch_b = (const float*)d_in[2];
  const float* Wq = (const float*)d_in[3];
  const float* bq = (const float*)d_in[4];
  const float* Wk = (const float*)d_in[5];
  const float* bk = (const float*)d_in[6];
  const float* Wv = (const float*)d_in[7];
  const float* bv = (const float*)d_in[8];
  const float* Wo = (const float*)d_in[9];
  const float* bo = (const float*)d_in[10];
  const float* ff1_W = (const float*)d_in[11];
  const float* ff1_b = (const float*)d_in[12];
  const float* ff2_W = (const float*)d_in[13];
  const float* ff2_b = (const float*)d_in[14];
  const float* n1_g = (const float*)d_in[15];
  const float* n1_b = (const float*)d_in[16];
  const float* n2_g = (const float*)d_in[17];
  const float* n2_b = (const float*)d_in[18];

  // fixed-size pieces (hA is ALIASED into vbufT: disjoint lifetimes --
  // vbufT live kv->attn; hA live wo_ln->ff2; stream serializes them)
  const size_t h_bytes = (size_t)TOK * EMB * sizeof(float);          // 13.76 MB
  const size_t hbf_bytes = (size_t)TOK * EMB * 2;                    // 6.88 MB
  const size_t heads_bytes = (size_t)TOK * NHEAD * HDIM * 2;         // 82.58 MB
  const size_t wqT_bytes = (size_t)NLAYER * NHEAD * HDIM * EMB * 2;  // 0.44 MB
  const size_t wkvT_bytes = 2 * wqT_bytes;                           // 0.88 MB
  const size_t woT_bytes = (size_t)NLAYER * EMB * NHEAD * HDIM * 2;  // 0.44 MB
  const size_t ffw_bytes = (size_t)NLAYER * FFDIM * EMB * 2;         // 0.10 MB
  const size_t fixed = h_bytes + hbf_bytes + heads_bytes + wqT_bytes +
                       wkvT_bytes + woT_bytes + 2 * ffw_bytes;       // 105.2 MB

  // Chunk merge (round 9): 1920-block attn launches run 2.5 occupancy
  // rounds (768 resident slots) -> quantizes to 3 rounds = ~17% tail idle.
  // chunk=64 -> 3840 blocks = exactly 5.0 rounds, no tail; halves launches.
  // Requires fixed + 2*82.58 = 270.3 MB (round-8 probe: ws < 284.1 MB, so
  // the hA->vbufT alias is what makes this attempt possible). Fallback: 32.
  const size_t kvb64 = (size_t)64 * NHEAD * SEQ * HDIM * 2;  // 82.58 MB
  const size_t kvb32 = (size_t)32 * NHEAD * SEQ * HDIM * 2;  // 41.29 MB
  int chunk = (ws_size >= fixed + 2 * kvb64) ? 64 : 32;
  const size_t kv_bytes = (chunk == 64) ? kvb64 : kvb32;

  char* ws = (char*)d_ws;
  size_t off = 0;
  float* h = (float*)(ws + off); off += h_bytes;
  __hip_bfloat16* hbf = (__hip_bfloat16*)(ws + off); off += hbf_bytes;
  __hip_bfloat16* kbuf = (__hip_bfloat16*)(ws + off); off += kv_bytes;
  __hip_bfloat16* vbufT = (__hip_bfloat16*)(ws + off); off += kv_bytes;
  __hip_bfloat16* heads = (__hip_bfloat16*)(ws + off); off += heads_bytes;
  __hip_bfloat16* wqT = (__hip_bfloat16*)(ws + off); off += wqT_bytes;
  __hip_bfloat16* wkvT = (__hip_bfloat16*)(ws + off); off += wkvT_bytes;
  __hip_bfloat16* woT = (__hip_bfloat16*)(ws + off); off += woT_bytes;
  __hip_bfloat16* ff1WT = (__hip_bfloat16*)(ws + off); off += ffw_bytes;
  __hip_bfloat16* ff2WT = (__hip_bfloat16*)(ws + off); off += ffw_bytes;
  float* hA = (float*)vbufT;                     // alias (13.76 <= kv_bytes)
  __hip_bfloat16* ffbf = (__hip_bfloat16*)kbuf;  // alias: free after attention

  allprep_kernel<<<78, 256, 0, stream>>>(Wq, Wk, Wv, Wo, ff1_W, ff2_W, wqT,
                                         wkvT, woT, ff1WT, ff2WT);
  patch_pe_kernel<<<(TOK * EMB + 255) / 256, 256, 0, stream>>>(x, patch_W,
                                                               patch_b, h, hbf);

  for (int l = 0; l < NLAYER; l++) {
    const __hip_bfloat16* wqT_l = wqT + (size_t)l * NHEAD * HDIM * EMB;
    const __hip_bfloat16* wkvT_l = wkvT + (size_t)l * 2 * NHEAD * HDIM * EMB;
    const __hip_bfloat16* woT_l = woT + (size_t)l * EMB * NHEAD * HDIM;
    const __hip_bfloat16* ff1WT_l = ff1WT + (size_t)l * FFDIM * EMB;
    const __hip_bfloat16* ff2WT_l = ff2WT + (size_t)l * EMB * FFDIM;
    const float* bq_l = bq + (size_t)l * NHEAD * HDIM;
    const float* bk_l = bk + (size_t)l * NHEAD * HDIM;
    const float* bv_l = bv + (size_t)l * NHEAD * HDIM;
    const float* bo_l = bo + (size_t)l * EMB;

    for (int c = 0; c < BATCH / chunk; c++) {
      int b0 = c * chunk;
      kv_mfma_kernel<<<dim3(chunk * SEQ / 64, 2 * NHEAD * HDIM / 64), 256, 0,
                       stream>>>(hbf, wkvT_l, bk_l, bv_l, kbuf, vbufT, b0);
      // 5 q-blocks (128 rows each) x (chunk*12) groups, XCD-swizzled
      attn_flash_kernel<<<5 * NHEAD * chunk, 256, 0, stream>>>(
          hbf, wqT_l, bq_l, kbuf, vbufT, heads, b0);
    }
    // LN1: reads residual h, writes hA (fp32, aliased over vbufT) + hbf
    wo_ln_mfma_kernel<<<TOK / 64, 256, 0, stream>>>(
        heads, woT_l, bo_l, n1_g + l * EMB, n1_b + l * EMB, h, hA, hbf);
    // FF path (MFMA, split, proven): ff1 reads hbf -> ffbf; ff2 reads ffbf + hA
    ff1_mfma_kernel<<<TOK / 64, 256, 0, stream>>>(hbf, ff1WT_l,
                                                  ff1_b + l * FFDIM, ffbf);
    float* dst = (l == NLAYER - 1) ? (float*)d_out : h;
    ff2_ln_mfma_kernel<<<TOK / 64, 256, 0, stream>>>(
        ffbf, ff2WT_l, ff2_b + l * EMB, n2_g + l * EMB, n2_b + l * EMB, hA,
        dst, hbf);
  }
}